// Round 2
// baseline (329.166 us; speedup 1.0000x reference)
//
#include <hip/hip_runtime.h>
#include <math.h>

// ---------------------------------------------------------------------------
// VQVAE forward. v11: conv2 keeps v10's 256x512 double-buffered structure but
// fixes vmcnt in-order poisoning: all 36 per-step weight loads are issued
// (into VGPRs) BEFORE the stage global_load_lds ops, so weight-consumption
// waits never force retirement of the HBM prefetch. Order pinned with
// sched_barrier(0). Staging tail is now an exec-masked global_load_lds
// (zero vmem->reg consumption in the staging path). ky loop force-unrolled
// so the weight register arrays stay statically indexed.
// ---------------------------------------------------------------------------

typedef _Float16 f16x8 __attribute__((ext_vector_type(8)));
typedef float f32x4 __attribute__((ext_vector_type(4)));

#define H1N 16777216        // elements per h1 plane; zero tail after
#define H1PL 16777280       // f16 offset between h1h and h1l planes
#define YTAIL (2048 * 128)  // zero page in Yh/Yl for OOB shifts

// ---------- prep: A-agg (0..127), W-split (128..143), cbT (144..151), misc --
__global__ __launch_bounds__(256) void k_prep(const float* __restrict__ w2,
                                              const float* __restrict__ w1,
                                              const float* __restrict__ wp,
                                              const float* __restrict__ wd,
                                              const float* __restrict__ wd1,
                                              const float* __restrict__ cb,
                                              float* __restrict__ w1t,
                                              float* __restrict__ wpT,
                                              float* __restrict__ wdT,
                                              float* __restrict__ cbT,
                                              _Float16* __restrict__ Ah,
                                              _Float16* __restrict__ Al,
                                              _Float16* __restrict__ Wh,
                                              _Float16* __restrict__ Wl,
                                              _Float16* __restrict__ h1h,
                                              _Float16* __restrict__ h1l) {
  int bx = blockIdx.x, tid = threadIdx.x;
  if (bx < 128) {  // ---- A aggregation, block = co, lanes = ci (writes coalesced)
    __shared__ float wrow[1152];
    int co = bx;
    for (int i = tid; i < 1152; i += 256) wrow[i] = wd1[co * 1152 + i];
    __syncthreads();
    if (tid < 128) {
      int ci = tid;
      float w[9];
#pragma unroll
      for (int t = 0; t < 9; t++) w[t] = wrow[ci * 9 + t];
      float rx[3][5];
#pragma unroll
      for (int ky = 0; ky < 3; ky++) {
        float a0 = w[ky * 3 + 0], a1 = w[ky * 3 + 1], a2 = w[ky * 3 + 2];
        rx[ky][0] = a0; rx[ky][1] = a1 + a2; rx[ky][2] = a0 + a1 + a2;
        rx[ky][3] = a0 + a1; rx[ky][4] = a2;
      }
#pragma unroll
      for (int px = 0; px < 5; px++) {
        float s0 = rx[0][px], s1 = rx[1][px], s2 = rx[2][px];
        float ry[5];
        ry[0] = s0; ry[1] = s1 + s2; ry[2] = s0 + s1 + s2; ry[3] = s0 + s1; ry[4] = s2;
#pragma unroll
        for (int py = 0; py < 5; py++) {
          int pq = py * 5 + px;
          float v = ry[py];
          _Float16 h = (_Float16)v;
          int o = (pq * 128 + co) * 128 + ci;
          Ah[o] = h;
          Al[o] = (_Float16)(v - (float)h);
        }
      }
    }
    return;
  }
  if (bx < 144) {  // ---- W f16-split: 8 co per block, LDS-staged, coalesced RW
    __shared__ float wst[9216];
    int co0 = (bx - 128) * 8;
    for (int i = tid; i < 9216; i += 256) wst[i] = w2[co0 * 1152 + i];
    __syncthreads();
    for (int i = tid; i < 9216; i += 256) {
      int co = i / 1152, r = i - co * 1152;
      int tap = r >> 7, ci = r & 127;
      float v = wst[co * 1152 + ci * 9 + tap];
      _Float16 h = (_Float16)v;
      int o = (tap * 128 + co0 + co) * 128 + ci;
      Wh[o] = h;
      Wl[o] = (_Float16)(v - (float)h);
    }
    return;
  }
  if (bx < 152) {  // ---- cbT tile transpose (64 k x 64 d), padded LDS
    __shared__ float cbs[64 * 65];
    int k0 = (bx - 144) * 64;
    for (int i = tid; i < 4096; i += 256) {
      int k = i >> 6, d = i & 63;
      cbs[k * 65 + d] = cb[(k0 + k) * 64 + d];
    }
    __syncthreads();
    for (int i = tid; i < 4096; i += 256) {
      int d = i >> 6, k = i & 63;
      cbT[d * 512 + k0 + k] = cbs[k * 65 + d];
    }
    return;
  }
  // ---- misc small transposes + h1 zero tails (writes lane-contiguous)
  for (int i = tid; i < 3456; i += 256) {  // w1t[t][co] = w1[co][t]
    int co = i & 127, t = i >> 7;
    w1t[t * 128 + co] = w1[co * 27 + t];
  }
  for (int i = tid; i < 8192; i += 256) {  // wpT[k][d] = wp[d][k]
    int d = i & 63, k = i >> 6;
    wpT[k * 64 + d] = wp[d * 128 + k];
  }
  for (int i = tid; i < 8192; i += 256) {  // wdT[d][co] = wd[co][d]
    int co = i & 127, d = i >> 7;
    wdT[d * 128 + co] = wd[co * 64 + d];
  }
  if (tid < 64) {
    h1h[H1N + tid] = (_Float16)0.f;
    h1l[H1N + tid] = (_Float16)0.f;
  }
}

// ---------- conv1: (32,3,128,128) -> h1 f16-split [g][b][oh][ow][8ci] -------
__global__ __launch_bounds__(256) void k_conv1(const float* __restrict__ x,
                                               const float* __restrict__ w1t,
                                               const float* __restrict__ b1,
                                               _Float16* __restrict__ h1h,
                                               _Float16* __restrict__ h1l) {
  __shared__ float E[3][9][68];
  __shared__ float O[3][9][68];
  int co_t = blockIdx.x, oh_t = blockIdx.y, b = blockIdx.z;
  int oh0 = oh_t * 4;
  int tid = threadIdx.x;
  int wv = __builtin_amdgcn_readfirstlane(tid >> 6);
  int l = tid & 63;
  int coB = co_t * 32 + wv * 8;

  for (int idx = tid; idx < 1728; idx += 256) {
    int p = idx & 63, r = idx >> 6;
    int ci = r / 9, lr = r - ci * 9;
    int ih = 2 * oh0 - 1 + lr;
    float2 v = make_float2(0.f, 0.f);
    if ((unsigned)ih < 128u)
      v = *(const float2*)&x[((b * 3 + ci) * 128 + ih) * 128 + 2 * p];
    E[ci][lr][p] = v.x;
    O[ci][lr][p + 1] = v.y;
  }
  if (tid < 27) {
    int ci = tid / 9, lr = tid - ci * 9;
    O[ci][lr][0] = 0.f;
  }
  __syncthreads();

  int ohl = l >> 4, ow0 = (l & 15) * 4;
  int oh = oh0 + ohl;
  float4 acc[8];
#pragma unroll
  for (int q = 0; q < 8; q++) {
    float bv = b1[coB + q];
    acc[q] = make_float4(bv, bv, bv, bv);
  }
#pragma unroll
  for (int ci = 0; ci < 3; ci++) {
#pragma unroll
    for (int ky = 0; ky < 3; ky++) {
      int lr = 2 * ohl + ky;
      float4 ev = *(float4*)&E[ci][lr][ow0];
      float4 od = *(float4*)&O[ci][lr][ow0];
      float o4 = O[ci][lr][ow0 + 4];
      const float* wr = w1t + (ci * 9 + ky * 3) * 128 + coB;
#pragma unroll
      for (int q = 0; q < 8; q++) {
        float wa = wr[q], wb = wr[128 + q], wc = wr[256 + q];
        acc[q].x = fmaf(wa, od.x, acc[q].x);
        acc[q].x = fmaf(wb, ev.x, acc[q].x);
        acc[q].x = fmaf(wc, od.y, acc[q].x);
        acc[q].y = fmaf(wa, od.y, acc[q].y);
        acc[q].y = fmaf(wb, ev.y, acc[q].y);
        acc[q].y = fmaf(wc, od.z, acc[q].y);
        acc[q].z = fmaf(wa, od.z, acc[q].z);
        acc[q].z = fmaf(wb, ev.z, acc[q].z);
        acc[q].z = fmaf(wc, od.w, acc[q].z);
        acc[q].w = fmaf(wa, od.w, acc[q].w);
        acc[q].w = fmaf(wb, ev.w, acc[q].w);
        acc[q].w = fmaf(wc, o4,   acc[q].w);
      }
    }
  }
  int g = coB >> 3;
  int pbase = ((g * 32 + b) * 64 + oh) * 64;
#pragma unroll
  for (int oi = 0; oi < 4; oi++) {
    f16x8 hv, lv;
#pragma unroll
    for (int q = 0; q < 8; q++) {
      float v = fmaxf(((const float*)&acc[q])[oi], 0.f);
      _Float16 h = (_Float16)v;
      float rem = v - (float)h;
      hv[q] = h;
      lv[q] = (_Float16)rem;
    }
    int base = (pbase + ow0 + oi) * 8;
    *(f16x8*)&h1h[base] = hv;
    *(f16x8*)&h1l[base] = lv;
  }
}

// ---------- conv2: f16-split MFMA, poison-free issue order ------------------
// grid 256 = (b(32) x ohq(8)); block 512 = 8 waves. wave w: co-group (w&3),
// output-row-group rw=(w>>2) -> rows oh0+2*rw .. oh0+2*rw+1 (4 rows/block).
// Per step: [36 weight loads -> VGPRs] sched_barrier [stage(nxt): 9+tail
// global_load_lds] sched_barrier [compute: lgkm waits + vmcnt(>=stage cnt)
// weight waits -- stage stays in flight] __syncthreads (drains stage under
// full compute overlap). In-order vmcnt retirement makes weight waits legal
// only because weights are issued OLDEST.
#define C2_CHUNKS 4680
#define C2_BUF (C2_CHUNKS * 8)  // f16 elems per buffer
#define C2_LDS (2 * C2_BUF * 2) // bytes = 149760
#define C2_STEP 4194304         // h1 element advance per +32ci step

__global__ __launch_bounds__(512, 2) void k_conv2(const _Float16* __restrict__ h1h,
                                                  const _Float16* __restrict__ Wh,
                                                  const _Float16* __restrict__ Wl,
                                                  const float* __restrict__ b2,
                                                  float* __restrict__ h2) {
  extern __shared__ _Float16 Bbuf[];
  int bx = blockIdx.x;
  int b = bx >> 3, ohq = bx & 7;
  int oh0 = ohq * 4;
  int tid = threadIdx.x;
  int w = tid >> 6, l = tid & 63;
  int cw = w & 3, rw = w >> 2;
  int ln = l & 15, quad = l >> 4;
  int coW = cw * 32;
  int kq = quad * 8;

  // ---- precompute staging descriptors: 10 chunks/thread (last partial) ----
  int cursrc[10];
  int adv[10];
#pragma unroll
  for (int k = 0; k < 10; k++) {
    int c = tid + k * 512;
    if (c < C2_CHUNKS) {
      int q = c / 65, rem = c - q * 65;
      int ph = rem >= 33;
      int u = ph ? rem - 33 : rem;
      int pl = q & 1, t = q >> 1;
      int r = t % 9, g = t / 9;
      int iw = ph ? 2 * u : 2 * u - 1;
      int ih = 2 * oh0 - 1 + r;
      bool ok = (ih >= 0) && (iw >= 0) && (iw < 64);
      cursrc[k] = pl * H1PL + (ok ? ((g * 32 + b) * 64 + ih) * 512 + iw * 8 : H1N);
      adv[k] = ok ? C2_STEP : 0;
    } else {
      cursrc[k] = H1N;
      adv[k] = 0;
    }
  }

#define C2_STAGE(DST)                                                          \
  {                                                                            \
    _Pragma("unroll") for (int k = 0; k < 9; k++) {                            \
      __builtin_amdgcn_global_load_lds(                                        \
          (const __attribute__((address_space(1))) void*)(h1h + cursrc[k]),    \
          (__attribute__((address_space(3))) void*)&Bbuf[(DST) +               \
                                                         (tid + k * 512) * 8], \
          16, 0, 0);                                                           \
      cursrc[k] += adv[k];                                                     \
    }                                                                          \
    if (tid < 72) {                                                            \
      __builtin_amdgcn_global_load_lds(                                        \
          (const __attribute__((address_space(1))) void*)(h1h + cursrc[9]),    \
          (__attribute__((address_space(3))) void*)&Bbuf[(DST) +               \
                                                         (tid + 9 * 512) * 8], \
          16, 0, 0);                                                           \
    }                                                                          \
    cursrc[9] += adv[9];                                                       \
  }

  int curoff = 0;
  C2_STAGE(0);        // prologue: stage K-step 0 into buffer 0
  __syncthreads();    // vmcnt(0)+lgkmcnt(0) drain + barrier

  f32x4 acc[2][4] = {};  // [cs][s]  s = (row-in-pair<<1)|col-half
  for (int step = 0; step < 4; step++) {
    int nxt = curoff ^ C2_BUF;
    const int ci0 = step * 32;

    // ---- 1) issue ALL of this step's weight loads first (oldest VMEM) ----
    f16x8 wAh0[9], wAl0[9], wAh1[9], wAl1[9];
#pragma unroll
    for (int tap = 0; tap < 9; tap++) {
      const int wbase = (tap * 128 + coW + ln) * 128 + ci0 + kq;
      wAh0[tap] = *(const f16x8*)&Wh[wbase];
      wAl0[tap] = *(const f16x8*)&Wl[wbase];
      wAh1[tap] = *(const f16x8*)&Wh[wbase + 2048];  // +16 co
      wAl1[tap] = *(const f16x8*)&Wl[wbase + 2048];
    }
    __builtin_amdgcn_sched_barrier(0);  // weights strictly before stage

    // ---- 2) issue next K-step's stage loads (youngest; drain at barrier) --
    if (step < 3) C2_STAGE(nxt);
    __builtin_amdgcn_sched_barrier(0);  // stage strictly before compute

    // ---- 3) compute: LDS reads + in-register weights ----
#pragma unroll
    for (int ky = 0; ky < 3; ky++) {
#pragma unroll
      for (int kx = 0; kx < 3; kx++) {
        int tap = ky * 3 + kx;
#pragma unroll
        for (int s = 0; s < 4; s++) {
          int owl = (s & 1) * 16 + ln;
          int r = 4 * rw + 2 * (s >> 1) + ky;
          int base = ((quad * 9 + r) * 2) * 65;
          int uoff = (kx == 1) ? (33 + owl) : (owl + (kx == 2));
          f16x8 Bh = *(const f16x8*)&Bbuf[curoff + (base + uoff) * 8];
          f16x8 Bl = *(const f16x8*)&Bbuf[curoff + (base + 65 + uoff) * 8];
          acc[0][s] = __builtin_amdgcn_mfma_f32_16x16x32_f16(wAl0[tap], Bh, acc[0][s], 0, 0, 0);
          acc[0][s] = __builtin_amdgcn_mfma_f32_16x16x32_f16(wAh0[tap], Bl, acc[0][s], 0, 0, 0);
          acc[0][s] = __builtin_amdgcn_mfma_f32_16x16x32_f16(wAh0[tap], Bh, acc[0][s], 0, 0, 0);
          acc[1][s] = __builtin_amdgcn_mfma_f32_16x16x32_f16(wAl1[tap], Bh, acc[1][s], 0, 0, 0);
          acc[1][s] = __builtin_amdgcn_mfma_f32_16x16x32_f16(wAh1[tap], Bl, acc[1][s], 0, 0, 0);
          acc[1][s] = __builtin_amdgcn_mfma_f32_16x16x32_f16(wAh1[tap], Bh, acc[1][s], 0, 0, 0);
        }
      }
    }
    __syncthreads();  // all waves' loads into nxt done; all done reading cur
    curoff = nxt;
  }
  // epilogue: C row = co (quad*4+reg), col = px (lane&15)
#pragma unroll
  for (int cs = 0; cs < 2; cs++)
#pragma unroll
    for (int s = 0; s < 4; s++) {
      int oh = oh0 + 2 * rw + (s >> 1);
      int ow = (s & 1) * 16 + ln;
#pragma unroll
      for (int r = 0; r < 4; r++) {
        int co = coW + cs * 16 + quad * 4 + r;
        h2[((b * 128 + co) * 32 + oh) * 32 + ow] = fmaxf(acc[cs][s][r] + b2[co], 0.f);
      }
    }
#undef C2_STAGE
}

// ---------- pool(4x4 mean) + proj(1x1,128->64); grid 128 (b x quarter) ------
__global__ __launch_bounds__(256) void k_poolproj(const float* __restrict__ h2,
                                                  const float* __restrict__ wpT,
                                                  const float* __restrict__ pb,
                                                  float* __restrict__ z_e_out,
                                                  float* __restrict__ lossacc) {
  __shared__ float hp[128][16];
  __shared__ float Ws[128][64];
  int bx = blockIdx.x, tid = threadIdx.x;
  int b = bx >> 2, quarter = bx & 3;
  if (bx == 0 && tid == 0) lossacc[0] = 0.f;
  for (int i = tid; i < 8192; i += 256) Ws[i >> 6][i & 63] = wpT[i];
  for (int i = tid; i < 2048; i += 256) {
    int ci = i >> 4, pl = i & 15;
    int pi = quarter * 16 + pl;
    int bi = pi >> 3, bj = pi & 7;
    const float* src = &h2[((b * 128 + ci) * 32 + bi * 4) * 32 + bj * 4];
    float4 r0 = *(const float4*)src;
    float4 r1 = *(const float4*)(src + 32);
    float4 r2 = *(const float4*)(src + 64);
    float4 r3 = *(const float4*)(src + 96);
    float s = r0.x + r0.y + r0.z + r0.w + r1.x + r1.y + r1.z + r1.w +
              r2.x + r2.y + r2.z + r2.w + r3.x + r3.y + r3.z + r3.w;
    hp[ci][pl] = s * 0.0625f;
  }
  __syncthreads();
  int d = tid >> 2, s0 = (tid & 3) * 4;
  float4 acc = make_float4(0.f, 0.f, 0.f, 0.f);
  for (int k = 0; k < 128; k++) {
    float a = Ws[k][d];
    float4 h = *(float4*)&hp[k][s0];
    acc.x = fmaf(a, h.x, acc.x);
    acc.y = fmaf(a, h.y, acc.y);
    acc.z = fmaf(a, h.z, acc.z);
    acc.w = fmaf(a, h.w, acc.w);
  }
  float bv = pb[d];
  float4 r4 = make_float4(acc.x + bv, acc.y + bv, acc.z + bv, acc.w + bv);
  *(float4*)&z_e_out[(b * 64 + d) * 64 + quarter * 16 + s0] = r4;
}

// ---------- VQ argmin + loss + dproj -> Yh/Yl f16 planes; grid 2048 ----------
__global__ __launch_bounds__(64) void k_vqdproj(const float* __restrict__ z_e,
                                                const float* __restrict__ cbT,
                                                const float* __restrict__ cb,
                                                const float* __restrict__ wdT,
                                                const float* __restrict__ db,
                                                float* __restrict__ idx_f,
                                                _Float16* __restrict__ Yh,
                                                _Float16* __restrict__ Yl,
                                                float* __restrict__ loss_acc) {
  __shared__ float zs[64];
  int n = blockIdx.x, lane = threadIdx.x;
  int b = n >> 6, pi = n & 63;
  zs[lane] = z_e[(b * 64 + lane) * 64 + pi];
  if (n == 0) {  // zero tail page for shifted reads in k_dec
    Yh[YTAIL + lane] = (_Float16)0.f;
    Yh[YTAIL + 64 + lane] = (_Float16)0.f;
    Yl[YTAIL + lane] = (_Float16)0.f;
    Yl[YTAIL + 64 + lane] = (_Float16)0.f;
  }
  __syncthreads();
  double best = 1e300;
  int bi = 0;
#pragma unroll 2
  for (int j = 0; j < 8; j++) {
    int k = j * 64 + lane;
    double a0 = 0.0, a1 = 0.0, a2 = 0.0, a3 = 0.0;
#pragma unroll 4
    for (int d = 0; d < 64; d += 4) {
      double f0 = (double)zs[d] - (double)cbT[d * 512 + k];
      double f1 = (double)zs[d + 1] - (double)cbT[(d + 1) * 512 + k];
      double f2 = (double)zs[d + 2] - (double)cbT[(d + 2) * 512 + k];
      double f3 = (double)zs[d + 3] - (double)cbT[(d + 3) * 512 + k];
      a0 = fma(f0, f0, a0);
      a1 = fma(f1, f1, a1);
      a2 = fma(f2, f2, a2);
      a3 = fma(f3, f3, a3);
    }
    double acc = (a0 + a1) + (a2 + a3);
    if (acc < best) { best = acc; bi = k; }
  }
  for (int m = 1; m < 64; m <<= 1) {
    double ob = __shfl_xor(best, m, 64);
    int oi = __shfl_xor(bi, m, 64);
    if (ob < best || (ob == best && oi < bi)) { best = ob; bi = oi; }
  }
  float zq_l = cb[bi * 64 + lane];
  float e = zq_l - zs[lane];
  float sq = e * e;
  for (int m = 1; m < 64; m <<= 1) sq += __shfl_xor(sq, m, 64);
  if (lane == 0) {
    idx_f[n] = (float)bi;
    atomicAdd(loss_acc, sq);
  }
  __syncthreads();
  zs[lane] = zq_l;
  __syncthreads();
  float a0 = db[lane], a1 = db[lane + 64];
#pragma unroll 4
  for (int d = 0; d < 64; d++) {
    float z = zs[d];
    a0 = fmaf(wdT[d * 128 + lane], z, a0);
    a1 = fmaf(wdT[d * 128 + lane + 64], z, a1);
  }
  float y0 = fmaxf(a0, 0.f), y1 = fmaxf(a1, 0.f);
  _Float16 h0 = (_Float16)y0, h1v = (_Float16)y1;
  Yh[n * 128 + lane] = h0;
  Yh[n * 128 + lane + 64] = h1v;
  Yl[n * 128 + lane] = (_Float16)(y0 - (float)h0);
  Yl[n * 128 + lane + 64] = (_Float16)(y1 - (float)h1v);
}

// ---------- dec: f16-split MFMA, G[pq][n][co] = A_pq * Yshift ----------
__global__ __launch_bounds__(256) void k_dec(const _Float16* __restrict__ Yh,
                                             const _Float16* __restrict__ Yl,
                                             const _Float16* __restrict__ Ah,
                                             const _Float16* __restrict__ Al,
                                             float* __restrict__ G) {
  int bxx = blockIdx.x;
  int pq = bxx >> 6, n_t = bxx & 63;
  int w = threadIdx.x >> 6, l = threadIdx.x & 63;
  int ln = l & 15, quad = l >> 4;
  int coW = w * 32;
  int nB = n_t * 32;
  int py = pq / 5, px = pq - py * 5;
  int dy = (py == 0) ? -1 : ((py == 4) ? 1 : 0);
  int dx = (px == 0) ? -1 : ((px == 4) ? 1 : 0);
  int src[2];
#pragma unroll
  for (int s = 0; s < 2; s++) {
    int n = nB + s * 16 + ln;
    int bb = n >> 6, s6 = n & 63;
    int sy = (s6 >> 3) + dy, sx = (s6 & 7) + dx;
    bool ok = ((unsigned)sy < 8u) && ((unsigned)sx < 8u);
    src[s] = ok ? ((bb * 64 + sy * 8 + sx) * 128) : YTAIL;
  }
  int kq = quad * 8;
  f32x4 acc[2][2] = {};
#pragma unroll 2
  for (int ci0 = 0; ci0 < 128; ci0 += 32) {
    const int wbase = (pq * 128 + coW + ln) * 128 + ci0 + kq;
    f16x8 Ah0 = *(const f16x8*)&Ah[wbase];
    f16x8 Al0 = *(const f16x8*)&Al[wbase];
    f16x8 Ah1 = *(const f16x8*)&Ah[wbase + 2048];
    f16x8 Al1 = *(const f16x8*)&Al[wbase + 2048];
    f16x8 Bh[2], Bl[2];
#pragma unroll
    for (int s = 0; s < 2; s++) {
      Bh[s] = *(const f16x8*)&Yh[src[s] + ci0 + kq];
      Bl[s] = *(const f16x8*)&Yl[src[s] + ci0 + kq];
    }
#pragma unroll
    for (int cs = 0; cs < 2; cs++) {
      f16x8 ah = cs ? Ah1 : Ah0;
      f16x8 al = cs ? Al1 : Al0;
#pragma unroll
      for (int s = 0; s < 2; s++) {
        acc[cs][s] = __builtin_amdgcn_mfma_f32_16x16x32_f16(al, Bh[s], acc[cs][s], 0, 0, 0);
        acc[cs][s] = __builtin_amdgcn_mfma_f32_16x16x32_f16(ah, Bl[s], acc[cs][s], 0, 0, 0);
        acc[cs][s] = __builtin_amdgcn_mfma_f32_16x16x32_f16(ah, Bh[s], acc[cs][s], 0, 0, 0);
      }
    }
  }
#pragma unroll
  for (int cs = 0; cs < 2; cs++)
#pragma unroll
    for (int s = 0; s < 2; s++) {
      int site = nB + s * 16 + ln;
      float4 g = make_float4(acc[cs][s][0], acc[cs][s][1], acc[cs][s][2], acc[cs][s][3]);
      *(float4*)&G[(pq * 2048 + site) * 128 + coW + cs * 16 + quad * 4] = g;
    }
}

// ---------- out: combine G per class, bias+relu, 1x1 conv to 3ch, splat ------
__global__ __launch_bounds__(256) void k_out(const float* __restrict__ G,
                                             const float* __restrict__ bc1,
                                             const float* __restrict__ w3,
                                             const float* __restrict__ b3,
                                             float* __restrict__ xhat,
                                             const float* __restrict__ loss_acc,
                                             float* __restrict__ out_loss) {
  __shared__ float Tb[9][128];
  __shared__ float part[9][3][8];
  __shared__ float vals[9][3];
  int bj = blockIdx.x, bi = blockIdx.y, b = blockIdx.z;
  int s = bi * 8 + bj;
  int n = b * 64 + s;
  int tid = threadIdx.x;
  if (bj == 0 && bi == 0 && b == 0 && tid == 0)
    out_loss[0] = loss_acc[0] * 1.25f / 131072.0f;
  int co = tid & 127, h = tid >> 7;
  const int rset[3][2] = {{0, 1}, {2, 2}, {3, 4}};
  const int rcnt[3] = {2, 1, 2};
  for (int cls = h; cls < 9; cls += 2) {
    int r = cls / 3, c = cls - r * 3;
    float sum = bc1[co];
    for (int iy = 0; iy < rcnt[r]; iy++) {
      int py = rset[r][iy];
      for (int ix = 0; ix < rcnt[c]; ix++) {
        int px = rset[c][ix];
        sum += G[((py * 5 + px) * 2048 + n) * 128 + co];
      }
    }
    Tb[cls][co] = fmaxf(sum, 0.f);
  }
  __syncthreads();
  if (tid < 216) {
    int cls = tid / 24, rem = tid - cls * 24;
    int cc = rem >> 3, seg = rem & 7;
    float ss = 0.f;
#pragma unroll
    for (int d = 0; d < 16; d++) ss = fmaf(w3[cc * 128 + seg * 16 + d], Tb[cls][seg * 16 + d], ss);
    part[cls][cc][seg] = ss;
  }
  __syncthreads();
  if (tid < 27) {
    int cls = tid / 3, cc = tid - cls * 3;
    float ss = b3[cc];
#pragma unroll
    for (int seg = 0; seg < 8; seg++) ss += part[cls][cc][seg];
    vals[cls][cc] = ss;
  }
  __syncthreads();
  for (int i = tid; i < 768; i += 256) {
    int cc = i >> 8, p = i & 255;
    int ry = p >> 4, rx = p & 15;
    int rcls = (ry == 0) ? 0 : ((ry == 15) ? 2 : 1);
    int ccls = (rx == 0) ? 0 : ((rx == 15) ? 2 : 1);
    xhat[((b * 3 + cc) * 128 + bi * 16 + ry) * 128 + bj * 16 + rx] =
        vals[rcls * 3 + ccls][cc];
  }
}

extern "C" void kernel_launch(void* const* d_in, const int* in_sizes, int n_in,
                              void* d_out, int out_size, void* d_ws, size_t ws_size,
                              hipStream_t stream) {
  const float* x   = (const float*)d_in[0];
  const float* w1  = (const float*)d_in[1];
  const float* b1  = (const float*)d_in[2];
  const float* w2  = (const float*)d_in[3];
  const float* b2  = (const float*)d_in[4];
  const float* wp  = (const float*)d_in[5];
  const float* pb  = (const float*)d_in[6];
  const float* cb  = (const float*)d_in[7];
  const float* wd  = (const float*)d_in[8];
  const float* db  = (const float*)d_in[9];
  const float* wc1 = (const float*)d_in[10];
  const float* bc1 = (const float*)d_in[11];
  const float* wc2 = (const float*)d_in[12];
  const float* bc2 = (const float*)d_in[13];
  float* out = (float*)d_out;
  float* ws  = (float*)d_ws;

  // workspace (float offsets):
  _Float16* h1h = (_Float16*)(ws);             // [0, 8388640)  (h1l = h1h + H1PL)
  _Float16* h1l = (_Float16*)(ws + 8388640);   // [8388640, 16777280)
  float* h2     = ws + 16777280;               // 4194304
  _Float16* Wh  = (_Float16*)(ws + 20971584);  // 73728 fl
  _Float16* Wl  = (_Float16*)(ws + 21045312);  // 73728 fl
  float* w1t    = ws + 21119040;               // 3456
  float* wpT    = ws + 21122496;               // 8192
  float* wdT    = ws + 21130688;               // 8192
  float* cbT    = ws + 21138880;               // 32768
  _Float16* Ahd = (_Float16*)(ws + 21171648);  // 204800 fl
  _Float16* Ald = (_Float16*)(ws + 21376448);  // 204800 fl -> end 21581248
  // overlays inside dead h1h/h1l region (valid after conv2):
  float* G       = ws;                         // [0, 6553600)
  _Float16* Yh   = (_Float16*)(ws + 6553600);  // 131136 fl (2049*128 f16)
  _Float16* Yl   = (_Float16*)(ws + 6684736);  // 131136 fl
  float* lossacc = ws + 6815872;               // 1

  float* o_xhat = out;
  float* o_idx  = out + 1572864;
  float* o_loss = out + 1574912;
  float* o_ze   = out + 1574913;

  static bool s_attr_done = false;
  if (!s_attr_done) {
    (void)hipFuncSetAttribute((const void*)k_conv2,
                              hipFuncAttributeMaxDynamicSharedMemorySize, C2_LDS);
    s_attr_done = true;
  }

  k_prep<<<dim3(153), 256, 0, stream>>>(w2, w1, wp, wd, wc1, cb,
                                        w1t, wpT, wdT, cbT, Ahd, Ald, Wh, Wl, h1h, h1l);
  k_conv1<<<dim3(4, 16, 32), 256, 0, stream>>>(x, w1t, b1, h1h, h1l);
  k_conv2<<<dim3(256), 512, C2_LDS, stream>>>(h1h, Wh, Wl, b2, h2);
  k_poolproj<<<dim3(128), 256, 0, stream>>>(h2, wpT, pb, o_ze, lossacc);
  k_vqdproj<<<dim3(2048), 64, 0, stream>>>(o_ze, cbT, cb, wdT, db, o_idx, Yh, Yl, lossacc);
  k_dec<<<dim3(1600), 256, 0, stream>>>(Yh, Yl, Ahd, Ald, G);
  k_out<<<dim3(8, 8, 32), 256, 0, stream>>>(G, bc1, wc2, bc2, o_xhat, lossacc, o_loss);
}

// Round 3
// 316.519 us; speedup vs baseline: 1.0400x; 1.0400x over previous
//
#include <hip/hip_runtime.h>
#include <math.h>

// ---------------------------------------------------------------------------
// VQVAE forward. v12: conv2 occupancy fix. 512 blocks x 512 threads (8 waves:
// 4 co-groups x 2 row-groups), 2 output rows/block, 5-row single-buffered
// 41.6 KB LDS tile -> 2 blocks/CU resident = 16 waves/CU = 4 waves/SIMD
// (double v10). Stage via global_load_lds, 2 barriers/step; cross-block TLP
// hides stage+load latency (v11's register-hoisting spilled: WRITE_SIZE
// 16->47 MB scratch traffic; reverted). Everything else unchanged from v10.
// ---------------------------------------------------------------------------

typedef _Float16 f16x8 __attribute__((ext_vector_type(8)));
typedef float f32x4 __attribute__((ext_vector_type(4)));

#define H1N 16777216        // elements per h1 plane; zero tail after
#define H1PL 16777280       // f16 offset between h1h and h1l planes
#define YTAIL (2048 * 128)  // zero page in Yh/Yl for OOB shifts

// ---------- prep: A-agg (0..127), W-split (128..143), cbT (144..151), misc --
__global__ __launch_bounds__(256) void k_prep(const float* __restrict__ w2,
                                              const float* __restrict__ w1,
                                              const float* __restrict__ wp,
                                              const float* __restrict__ wd,
                                              const float* __restrict__ wd1,
                                              const float* __restrict__ cb,
                                              float* __restrict__ w1t,
                                              float* __restrict__ wpT,
                                              float* __restrict__ wdT,
                                              float* __restrict__ cbT,
                                              _Float16* __restrict__ Ah,
                                              _Float16* __restrict__ Al,
                                              _Float16* __restrict__ Wh,
                                              _Float16* __restrict__ Wl,
                                              _Float16* __restrict__ h1h,
                                              _Float16* __restrict__ h1l) {
  int bx = blockIdx.x, tid = threadIdx.x;
  if (bx < 128) {  // ---- A aggregation, block = co, lanes = ci (writes coalesced)
    __shared__ float wrow[1152];
    int co = bx;
    for (int i = tid; i < 1152; i += 256) wrow[i] = wd1[co * 1152 + i];
    __syncthreads();
    if (tid < 128) {
      int ci = tid;
      float w[9];
#pragma unroll
      for (int t = 0; t < 9; t++) w[t] = wrow[ci * 9 + t];
      float rx[3][5];
#pragma unroll
      for (int ky = 0; ky < 3; ky++) {
        float a0 = w[ky * 3 + 0], a1 = w[ky * 3 + 1], a2 = w[ky * 3 + 2];
        rx[ky][0] = a0; rx[ky][1] = a1 + a2; rx[ky][2] = a0 + a1 + a2;
        rx[ky][3] = a0 + a1; rx[ky][4] = a2;
      }
#pragma unroll
      for (int px = 0; px < 5; px++) {
        float s0 = rx[0][px], s1 = rx[1][px], s2 = rx[2][px];
        float ry[5];
        ry[0] = s0; ry[1] = s1 + s2; ry[2] = s0 + s1 + s2; ry[3] = s0 + s1; ry[4] = s2;
#pragma unroll
        for (int py = 0; py < 5; py++) {
          int pq = py * 5 + px;
          float v = ry[py];
          _Float16 h = (_Float16)v;
          int o = (pq * 128 + co) * 128 + ci;
          Ah[o] = h;
          Al[o] = (_Float16)(v - (float)h);
        }
      }
    }
    return;
  }
  if (bx < 144) {  // ---- W f16-split: 8 co per block, LDS-staged, coalesced RW
    __shared__ float wst[9216];
    int co0 = (bx - 128) * 8;
    for (int i = tid; i < 9216; i += 256) wst[i] = w2[co0 * 1152 + i];
    __syncthreads();
    for (int i = tid; i < 9216; i += 256) {
      int co = i / 1152, r = i - co * 1152;
      int tap = r >> 7, ci = r & 127;
      float v = wst[co * 1152 + ci * 9 + tap];
      _Float16 h = (_Float16)v;
      int o = (tap * 128 + co0 + co) * 128 + ci;
      Wh[o] = h;
      Wl[o] = (_Float16)(v - (float)h);
    }
    return;
  }
  if (bx < 152) {  // ---- cbT tile transpose (64 k x 64 d), padded LDS
    __shared__ float cbs[64 * 65];
    int k0 = (bx - 144) * 64;
    for (int i = tid; i < 4096; i += 256) {
      int k = i >> 6, d = i & 63;
      cbs[k * 65 + d] = cb[(k0 + k) * 64 + d];
    }
    __syncthreads();
    for (int i = tid; i < 4096; i += 256) {
      int d = i >> 6, k = i & 63;
      cbT[d * 512 + k0 + k] = cbs[k * 65 + d];
    }
    return;
  }
  // ---- misc small transposes + h1 zero tails (writes lane-contiguous)
  for (int i = tid; i < 3456; i += 256) {  // w1t[t][co] = w1[co][t]
    int co = i & 127, t = i >> 7;
    w1t[t * 128 + co] = w1[co * 27 + t];
  }
  for (int i = tid; i < 8192; i += 256) {  // wpT[k][d] = wp[d][k]
    int d = i & 63, k = i >> 6;
    wpT[k * 64 + d] = wp[d * 128 + k];
  }
  for (int i = tid; i < 8192; i += 256) {  // wdT[d][co] = wd[co][d]
    int co = i & 127, d = i >> 7;
    wdT[d * 128 + co] = wd[co * 64 + d];
  }
  if (tid < 64) {
    h1h[H1N + tid] = (_Float16)0.f;
    h1l[H1N + tid] = (_Float16)0.f;
  }
}

// ---------- conv1: (32,3,128,128) -> h1 f16-split [g][b][oh][ow][8ci] -------
__global__ __launch_bounds__(256) void k_conv1(const float* __restrict__ x,
                                               const float* __restrict__ w1t,
                                               const float* __restrict__ b1,
                                               _Float16* __restrict__ h1h,
                                               _Float16* __restrict__ h1l) {
  __shared__ float E[3][9][68];
  __shared__ float O[3][9][68];
  int co_t = blockIdx.x, oh_t = blockIdx.y, b = blockIdx.z;
  int oh0 = oh_t * 4;
  int tid = threadIdx.x;
  int wv = __builtin_amdgcn_readfirstlane(tid >> 6);
  int l = tid & 63;
  int coB = co_t * 32 + wv * 8;

  for (int idx = tid; idx < 1728; idx += 256) {
    int p = idx & 63, r = idx >> 6;
    int ci = r / 9, lr = r - ci * 9;
    int ih = 2 * oh0 - 1 + lr;
    float2 v = make_float2(0.f, 0.f);
    if ((unsigned)ih < 128u)
      v = *(const float2*)&x[((b * 3 + ci) * 128 + ih) * 128 + 2 * p];
    E[ci][lr][p] = v.x;
    O[ci][lr][p + 1] = v.y;
  }
  if (tid < 27) {
    int ci = tid / 9, lr = tid - ci * 9;
    O[ci][lr][0] = 0.f;
  }
  __syncthreads();

  int ohl = l >> 4, ow0 = (l & 15) * 4;
  int oh = oh0 + ohl;
  float4 acc[8];
#pragma unroll
  for (int q = 0; q < 8; q++) {
    float bv = b1[coB + q];
    acc[q] = make_float4(bv, bv, bv, bv);
  }
#pragma unroll
  for (int ci = 0; ci < 3; ci++) {
#pragma unroll
    for (int ky = 0; ky < 3; ky++) {
      int lr = 2 * ohl + ky;
      float4 ev = *(float4*)&E[ci][lr][ow0];
      float4 od = *(float4*)&O[ci][lr][ow0];
      float o4 = O[ci][lr][ow0 + 4];
      const float* wr = w1t + (ci * 9 + ky * 3) * 128 + coB;
#pragma unroll
      for (int q = 0; q < 8; q++) {
        float wa = wr[q], wb = wr[128 + q], wc = wr[256 + q];
        acc[q].x = fmaf(wa, od.x, acc[q].x);
        acc[q].x = fmaf(wb, ev.x, acc[q].x);
        acc[q].x = fmaf(wc, od.y, acc[q].x);
        acc[q].y = fmaf(wa, od.y, acc[q].y);
        acc[q].y = fmaf(wb, ev.y, acc[q].y);
        acc[q].y = fmaf(wc, od.z, acc[q].y);
        acc[q].z = fmaf(wa, od.z, acc[q].z);
        acc[q].z = fmaf(wb, ev.z, acc[q].z);
        acc[q].z = fmaf(wc, od.w, acc[q].z);
        acc[q].w = fmaf(wa, od.w, acc[q].w);
        acc[q].w = fmaf(wb, ev.w, acc[q].w);
        acc[q].w = fmaf(wc, o4,   acc[q].w);
      }
    }
  }
  int g = coB >> 3;
  int pbase = ((g * 32 + b) * 64 + oh) * 64;
#pragma unroll
  for (int oi = 0; oi < 4; oi++) {
    f16x8 hv, lv;
#pragma unroll
    for (int q = 0; q < 8; q++) {
      float v = fmaxf(((const float*)&acc[q])[oi], 0.f);
      _Float16 h = (_Float16)v;
      float rem = v - (float)h;
      hv[q] = h;
      lv[q] = (_Float16)rem;
    }
    int base = (pbase + ow0 + oi) * 8;
    *(f16x8*)&h1h[base] = hv;
    *(f16x8*)&h1l[base] = lv;
  }
}

// ---------- conv2: f16-split MFMA; 512 blocks x 8 waves, 2 blocks/CU --------
// grid 512 = (b(32) x ohp(16)); block 512 = 8 waves. wave w: co-group (w&3),
// output row rw=(w>>2) -> oh = ohp*2 + rw. Wave computes 32co x 32px,
// acc[2][2]. LDS B (41.6 KB, single buffer): chunk c =
// ((g*5 + r)*2 + pl)*65 + (ph? 33+u : u), g=ci8-group(4), r=row(5:
// ih=2*oh0-1+r), pl=plane, ph=0: iw=2u-1, ph=1: iw=2u. Stage: 5 full
// 512-thread global_load_lds rounds + 40-chunk masked tail; 2 barriers/step.
// 2 blocks/CU (16 waves/CU) provide the latency hiding v9/v10 lacked.
#define C2_CHUNKS 2600
#define C2_STEP 4194304  // h1 element advance per +32ci step

__global__ __launch_bounds__(512, 4) void k_conv2(const _Float16* __restrict__ h1h,
                                                  const _Float16* __restrict__ Wh,
                                                  const _Float16* __restrict__ Wl,
                                                  const float* __restrict__ b2,
                                                  float* __restrict__ h2) {
  __shared__ _Float16 Bbuf[C2_CHUNKS * 8];  // 41600 B
  int bx = blockIdx.x;
  int b = bx >> 4, ohp = bx & 15;
  int oh0 = ohp * 2;
  int tid = threadIdx.x;
  int w = tid >> 6, l = tid & 63;
  int cw = w & 3, rw = w >> 2;
  int ln = l & 15, quad = l >> 4;
  int coW = cw * 32;
  int kq = quad * 8;

  // ---- precompute staging descriptors: 6 chunks/thread (last partial) ----
  int cursrc[6];
  int adv[6];
#pragma unroll
  for (int k = 0; k < 6; k++) {
    int c = tid + k * 512;
    if (c < C2_CHUNKS) {
      int q = c / 65, rem = c - q * 65;
      int ph = rem >= 33;
      int u = ph ? rem - 33 : rem;
      int pl = q & 1, t = q >> 1;
      int r = t % 5, g = t / 5;
      int iw = ph ? 2 * u : 2 * u - 1;
      int ih = 2 * oh0 - 1 + r;
      bool ok = (ih >= 0) && (iw >= 0) && (iw < 64);
      cursrc[k] = pl * H1PL + (ok ? ((g * 32 + b) * 64 + ih) * 512 + iw * 8 : H1N);
      adv[k] = ok ? C2_STEP : 0;
    } else {
      cursrc[k] = H1N;
      adv[k] = 0;
    }
  }

  f32x4 acc[2][2] = {};  // [cs][sc]
  for (int step = 0; step < 4; step++) {
    if (step) __syncthreads();  // prior compute done reading Bbuf
#pragma unroll
    for (int k = 0; k < 5; k++) {
      __builtin_amdgcn_global_load_lds(
          (const __attribute__((address_space(1))) void*)(h1h + cursrc[k]),
          (__attribute__((address_space(3))) void*)&Bbuf[(tid + k * 512) * 8],
          16, 0, 0);
      cursrc[k] += adv[k];
    }
    if (tid < 40)
      __builtin_amdgcn_global_load_lds(
          (const __attribute__((address_space(1))) void*)(h1h + cursrc[5]),
          (__attribute__((address_space(3))) void*)&Bbuf[(2560 + tid) * 8],
          16, 0, 0);
    cursrc[5] += adv[5];
    __syncthreads();  // drains vmcnt; stage complete

    const int ci0 = step * 32;
#pragma unroll
    for (int ky = 0; ky < 3; ky++) {
#pragma unroll
      for (int kx = 0; kx < 3; kx++) {
        int tap = ky * 3 + kx;
        const int wbase = (tap * 128 + coW + ln) * 128 + ci0 + kq;
        f16x8 Ah0 = *(const f16x8*)&Wh[wbase];
        f16x8 Al0 = *(const f16x8*)&Wl[wbase];
        f16x8 Ah1 = *(const f16x8*)&Wh[wbase + 2048];  // +16 co
        f16x8 Al1 = *(const f16x8*)&Wl[wbase + 2048];
        int r = 2 * rw + ky;
        int base = ((quad * 5 + r) * 2) * 65;
#pragma unroll
        for (int sc = 0; sc < 2; sc++) {
          int owl = sc * 16 + ln;
          int uoff = (kx == 1) ? (33 + owl) : (owl + (kx == 2));
          f16x8 Bh = *(const f16x8*)&Bbuf[(base + uoff) * 8];
          f16x8 Bl = *(const f16x8*)&Bbuf[(base + 65 + uoff) * 8];
          acc[0][sc] = __builtin_amdgcn_mfma_f32_16x16x32_f16(Al0, Bh, acc[0][sc], 0, 0, 0);
          acc[0][sc] = __builtin_amdgcn_mfma_f32_16x16x32_f16(Ah0, Bl, acc[0][sc], 0, 0, 0);
          acc[0][sc] = __builtin_amdgcn_mfma_f32_16x16x32_f16(Ah0, Bh, acc[0][sc], 0, 0, 0);
          acc[1][sc] = __builtin_amdgcn_mfma_f32_16x16x32_f16(Al1, Bh, acc[1][sc], 0, 0, 0);
          acc[1][sc] = __builtin_amdgcn_mfma_f32_16x16x32_f16(Ah1, Bl, acc[1][sc], 0, 0, 0);
          acc[1][sc] = __builtin_amdgcn_mfma_f32_16x16x32_f16(Ah1, Bh, acc[1][sc], 0, 0, 0);
        }
      }
    }
  }
  // epilogue: C row = co (quad*4+reg), col = px (lane&15)
  int oh = oh0 + rw;
#pragma unroll
  for (int cs = 0; cs < 2; cs++)
#pragma unroll
    for (int sc = 0; sc < 2; sc++) {
      int ow = sc * 16 + ln;
#pragma unroll
      for (int r2 = 0; r2 < 4; r2++) {
        int co = coW + cs * 16 + quad * 4 + r2;
        h2[((b * 128 + co) * 32 + oh) * 32 + ow] = fmaxf(acc[cs][sc][r2] + b2[co], 0.f);
      }
    }
}

// ---------- pool(4x4 mean) + proj(1x1,128->64); grid 128 (b x quarter) ------
__global__ __launch_bounds__(256) void k_poolproj(const float* __restrict__ h2,
                                                  const float* __restrict__ wpT,
                                                  const float* __restrict__ pb,
                                                  float* __restrict__ z_e_out,
                                                  float* __restrict__ lossacc) {
  __shared__ float hp[128][16];
  __shared__ float Ws[128][64];
  int bx = blockIdx.x, tid = threadIdx.x;
  int b = bx >> 2, quarter = bx & 3;
  if (bx == 0 && tid == 0) lossacc[0] = 0.f;
  for (int i = tid; i < 8192; i += 256) Ws[i >> 6][i & 63] = wpT[i];
  for (int i = tid; i < 2048; i += 256) {
    int ci = i >> 4, pl = i & 15;
    int pi = quarter * 16 + pl;
    int bi = pi >> 3, bj = pi & 7;
    const float* src = &h2[((b * 128 + ci) * 32 + bi * 4) * 32 + bj * 4];
    float4 r0 = *(const float4*)src;
    float4 r1 = *(const float4*)(src + 32);
    float4 r2 = *(const float4*)(src + 64);
    float4 r3 = *(const float4*)(src + 96);
    float s = r0.x + r0.y + r0.z + r0.w + r1.x + r1.y + r1.z + r1.w +
              r2.x + r2.y + r2.z + r2.w + r3.x + r3.y + r3.z + r3.w;
    hp[ci][pl] = s * 0.0625f;
  }
  __syncthreads();
  int d = tid >> 2, s0 = (tid & 3) * 4;
  float4 acc = make_float4(0.f, 0.f, 0.f, 0.f);
  for (int k = 0; k < 128; k++) {
    float a = Ws[k][d];
    float4 h = *(float4*)&hp[k][s0];
    acc.x = fmaf(a, h.x, acc.x);
    acc.y = fmaf(a, h.y, acc.y);
    acc.z = fmaf(a, h.z, acc.z);
    acc.w = fmaf(a, h.w, acc.w);
  }
  float bv = pb[d];
  float4 r4 = make_float4(acc.x + bv, acc.y + bv, acc.z + bv, acc.w + bv);
  *(float4*)&z_e_out[(b * 64 + d) * 64 + quarter * 16 + s0] = r4;
}

// ---------- VQ argmin + loss + dproj -> Yh/Yl f16 planes; grid 2048 ----------
__global__ __launch_bounds__(64) void k_vqdproj(const float* __restrict__ z_e,
                                                const float* __restrict__ cbT,
                                                const float* __restrict__ cb,
                                                const float* __restrict__ wdT,
                                                const float* __restrict__ db,
                                                float* __restrict__ idx_f,
                                                _Float16* __restrict__ Yh,
                                                _Float16* __restrict__ Yl,
                                                float* __restrict__ loss_acc) {
  __shared__ float zs[64];
  int n = blockIdx.x, lane = threadIdx.x;
  int b = n >> 6, pi = n & 63;
  zs[lane] = z_e[(b * 64 + lane) * 64 + pi];
  if (n == 0) {  // zero tail page for shifted reads in k_dec
    Yh[YTAIL + lane] = (_Float16)0.f;
    Yh[YTAIL + 64 + lane] = (_Float16)0.f;
    Yl[YTAIL + lane] = (_Float16)0.f;
    Yl[YTAIL + 64 + lane] = (_Float16)0.f;
  }
  __syncthreads();
  double best = 1e300;
  int bi = 0;
#pragma unroll 2
  for (int j = 0; j < 8; j++) {
    int k = j * 64 + lane;
    double a0 = 0.0, a1 = 0.0, a2 = 0.0, a3 = 0.0;
#pragma unroll 4
    for (int d = 0; d < 64; d += 4) {
      double f0 = (double)zs[d] - (double)cbT[d * 512 + k];
      double f1 = (double)zs[d + 1] - (double)cbT[(d + 1) * 512 + k];
      double f2 = (double)zs[d + 2] - (double)cbT[(d + 2) * 512 + k];
      double f3 = (double)zs[d + 3] - (double)cbT[(d + 3) * 512 + k];
      a0 = fma(f0, f0, a0);
      a1 = fma(f1, f1, a1);
      a2 = fma(f2, f2, a2);
      a3 = fma(f3, f3, a3);
    }
    double acc = (a0 + a1) + (a2 + a3);
    if (acc < best) { best = acc; bi = k; }
  }
  for (int m = 1; m < 64; m <<= 1) {
    double ob = __shfl_xor(best, m, 64);
    int oi = __shfl_xor(bi, m, 64);
    if (ob < best || (ob == best && oi < bi)) { best = ob; bi = oi; }
  }
  float zq_l = cb[bi * 64 + lane];
  float e = zq_l - zs[lane];
  float sq = e * e;
  for (int m = 1; m < 64; m <<= 1) sq += __shfl_xor(sq, m, 64);
  if (lane == 0) {
    idx_f[n] = (float)bi;
    atomicAdd(loss_acc, sq);
  }
  __syncthreads();
  zs[lane] = zq_l;
  __syncthreads();
  float a0 = db[lane], a1 = db[lane + 64];
#pragma unroll 4
  for (int d = 0; d < 64; d++) {
    float z = zs[d];
    a0 = fmaf(wdT[d * 128 + lane], z, a0);
    a1 = fmaf(wdT[d * 128 + lane + 64], z, a1);
  }
  float y0 = fmaxf(a0, 0.f), y1 = fmaxf(a1, 0.f);
  _Float16 h0 = (_Float16)y0, h1v = (_Float16)y1;
  Yh[n * 128 + lane] = h0;
  Yh[n * 128 + lane + 64] = h1v;
  Yl[n * 128 + lane] = (_Float16)(y0 - (float)h0);
  Yl[n * 128 + lane + 64] = (_Float16)(y1 - (float)h1v);
}

// ---------- dec: f16-split MFMA, G[pq][n][co] = A_pq * Yshift ----------
__global__ __launch_bounds__(256) void k_dec(const _Float16* __restrict__ Yh,
                                             const _Float16* __restrict__ Yl,
                                             const _Float16* __restrict__ Ah,
                                             const _Float16* __restrict__ Al,
                                             float* __restrict__ G) {
  int bxx = blockIdx.x;
  int pq = bxx >> 6, n_t = bxx & 63;
  int w = threadIdx.x >> 6, l = threadIdx.x & 63;
  int ln = l & 15, quad = l >> 4;
  int coW = w * 32;
  int nB = n_t * 32;
  int py = pq / 5, px = pq - py * 5;
  int dy = (py == 0) ? -1 : ((py == 4) ? 1 : 0);
  int dx = (px == 0) ? -1 : ((px == 4) ? 1 : 0);
  int src[2];
#pragma unroll
  for (int s = 0; s < 2; s++) {
    int n = nB + s * 16 + ln;
    int bb = n >> 6, s6 = n & 63;
    int sy = (s6 >> 3) + dy, sx = (s6 & 7) + dx;
    bool ok = ((unsigned)sy < 8u) && ((unsigned)sx < 8u);
    src[s] = ok ? ((bb * 64 + sy * 8 + sx) * 128) : YTAIL;
  }
  int kq = quad * 8;
  f32x4 acc[2][2] = {};
#pragma unroll 2
  for (int ci0 = 0; ci0 < 128; ci0 += 32) {
    const int wbase = (pq * 128 + coW + ln) * 128 + ci0 + kq;
    f16x8 Ah0 = *(const f16x8*)&Ah[wbase];
    f16x8 Al0 = *(const f16x8*)&Al[wbase];
    f16x8 Ah1 = *(const f16x8*)&Ah[wbase + 2048];
    f16x8 Al1 = *(const f16x8*)&Al[wbase + 2048];
    f16x8 Bh[2], Bl[2];
#pragma unroll
    for (int s = 0; s < 2; s++) {
      Bh[s] = *(const f16x8*)&Yh[src[s] + ci0 + kq];
      Bl[s] = *(const f16x8*)&Yl[src[s] + ci0 + kq];
    }
#pragma unroll
    for (int cs = 0; cs < 2; cs++) {
      f16x8 ah = cs ? Ah1 : Ah0;
      f16x8 al = cs ? Al1 : Al0;
#pragma unroll
      for (int s = 0; s < 2; s++) {
        acc[cs][s] = __builtin_amdgcn_mfma_f32_16x16x32_f16(al, Bh[s], acc[cs][s], 0, 0, 0);
        acc[cs][s] = __builtin_amdgcn_mfma_f32_16x16x32_f16(ah, Bl[s], acc[cs][s], 0, 0, 0);
        acc[cs][s] = __builtin_amdgcn_mfma_f32_16x16x32_f16(ah, Bh[s], acc[cs][s], 0, 0, 0);
      }
    }
  }
#pragma unroll
  for (int cs = 0; cs < 2; cs++)
#pragma unroll
    for (int s = 0; s < 2; s++) {
      int site = nB + s * 16 + ln;
      float4 g = make_float4(acc[cs][s][0], acc[cs][s][1], acc[cs][s][2], acc[cs][s][3]);
      *(float4*)&G[(pq * 2048 + site) * 128 + coW + cs * 16 + quad * 4] = g;
    }
}

// ---------- out: combine G per class, bias+relu, 1x1 conv to 3ch, splat ------
__global__ __launch_bounds__(256) void k_out(const float* __restrict__ G,
                                             const float* __restrict__ bc1,
                                             const float* __restrict__ w3,
                                             const float* __restrict__ b3,
                                             float* __restrict__ xhat,
                                             const float* __restrict__ loss_acc,
                                             float* __restrict__ out_loss) {
  __shared__ float Tb[9][128];
  __shared__ float part[9][3][8];
  __shared__ float vals[9][3];
  int bj = blockIdx.x, bi = blockIdx.y, b = blockIdx.z;
  int s = bi * 8 + bj;
  int n = b * 64 + s;
  int tid = threadIdx.x;
  if (bj == 0 && bi == 0 && b == 0 && tid == 0)
    out_loss[0] = loss_acc[0] * 1.25f / 131072.0f;
  int co = tid & 127, h = tid >> 7;
  const int rset[3][2] = {{0, 1}, {2, 2}, {3, 4}};
  const int rcnt[3] = {2, 1, 2};
  for (int cls = h; cls < 9; cls += 2) {
    int r = cls / 3, c = cls - r * 3;
    float sum = bc1[co];
    for (int iy = 0; iy < rcnt[r]; iy++) {
      int py = rset[r][iy];
      for (int ix = 0; ix < rcnt[c]; ix++) {
        int px = rset[c][ix];
        sum += G[((py * 5 + px) * 2048 + n) * 128 + co];
      }
    }
    Tb[cls][co] = fmaxf(sum, 0.f);
  }
  __syncthreads();
  if (tid < 216) {
    int cls = tid / 24, rem = tid - cls * 24;
    int cc = rem >> 3, seg = rem & 7;
    float ss = 0.f;
#pragma unroll
    for (int d = 0; d < 16; d++) ss = fmaf(w3[cc * 128 + seg * 16 + d], Tb[cls][seg * 16 + d], ss);
    part[cls][cc][seg] = ss;
  }
  __syncthreads();
  if (tid < 27) {
    int cls = tid / 3, cc = tid - cls * 3;
    float ss = b3[cc];
#pragma unroll
    for (int seg = 0; seg < 8; seg++) ss += part[cls][cc][seg];
    vals[cls][cc] = ss;
  }
  __syncthreads();
  for (int i = tid; i < 768; i += 256) {
    int cc = i >> 8, p = i & 255;
    int ry = p >> 4, rx = p & 15;
    int rcls = (ry == 0) ? 0 : ((ry == 15) ? 2 : 1);
    int ccls = (rx == 0) ? 0 : ((rx == 15) ? 2 : 1);
    xhat[((b * 3 + cc) * 128 + bi * 16 + ry) * 128 + bj * 16 + rx] =
        vals[rcls * 3 + ccls][cc];
  }
}

extern "C" void kernel_launch(void* const* d_in, const int* in_sizes, int n_in,
                              void* d_out, int out_size, void* d_ws, size_t ws_size,
                              hipStream_t stream) {
  const float* x   = (const float*)d_in[0];
  const float* w1  = (const float*)d_in[1];
  const float* b1  = (const float*)d_in[2];
  const float* w2  = (const float*)d_in[3];
  const float* b2  = (const float*)d_in[4];
  const float* wp  = (const float*)d_in[5];
  const float* pb  = (const float*)d_in[6];
  const float* cb  = (const float*)d_in[7];
  const float* wd  = (const float*)d_in[8];
  const float* db  = (const float*)d_in[9];
  const float* wc1 = (const float*)d_in[10];
  const float* bc1 = (const float*)d_in[11];
  const float* wc2 = (const float*)d_in[12];
  const float* bc2 = (const float*)d_in[13];
  float* out = (float*)d_out;
  float* ws  = (float*)d_ws;

  // workspace (float offsets):
  _Float16* h1h = (_Float16*)(ws);             // [0, 8388640)  (h1l = h1h + H1PL)
  _Float16* h1l = (_Float16*)(ws + 8388640);   // [8388640, 16777280)
  float* h2     = ws + 16777280;               // 4194304
  _Float16* Wh  = (_Float16*)(ws + 20971584);  // 73728 fl
  _Float16* Wl  = (_Float16*)(ws + 21045312);  // 73728 fl
  float* w1t    = ws + 21119040;               // 3456
  float* wpT    = ws + 21122496;               // 8192
  float* wdT    = ws + 21130688;               // 8192
  float* cbT    = ws + 21138880;               // 32768
  _Float16* Ahd = (_Float16*)(ws + 21171648);  // 204800 fl
  _Float16* Ald = (_Float16*)(ws + 21376448);  // 204800 fl -> end 21581248
  // overlays inside dead h1h/h1l region (valid after conv2):
  float* G       = ws;                         // [0, 6553600)
  _Float16* Yh   = (_Float16*)(ws + 6553600);  // 131136 fl (2049*128 f16)
  _Float16* Yl   = (_Float16*)(ws + 6684736);  // 131136 fl
  float* lossacc = ws + 6815872;               // 1

  float* o_xhat = out;
  float* o_idx  = out + 1572864;
  float* o_loss = out + 1574912;
  float* o_ze   = out + 1574913;

  k_prep<<<dim3(153), 256, 0, stream>>>(w2, w1, wp, wd, wc1, cb,
                                        w1t, wpT, wdT, cbT, Ahd, Ald, Wh, Wl, h1h, h1l);
  k_conv1<<<dim3(4, 16, 32), 256, 0, stream>>>(x, w1t, b1, h1h, h1l);
  k_conv2<<<dim3(512), 512, 0, stream>>>(h1h, Wh, Wl, b2, h2);
  k_poolproj<<<dim3(128), 256, 0, stream>>>(h2, wpT, pb, o_ze, lossacc);
  k_vqdproj<<<dim3(2048), 64, 0, stream>>>(o_ze, cbT, cb, wdT, db, o_idx, Yh, Yl, lossacc);
  k_dec<<<dim3(1600), 256, 0, stream>>>(Yh, Yl, Ahd, Ald, G);
  k_out<<<dim3(8, 8, 32), 256, 0, stream>>>(G, bc1, wc2, bc2, o_xhat, lossacc, o_loss);
}

// Round 4
// 309.958 us; speedup vs baseline: 1.0620x; 1.0212x over previous
//
#include <hip/hip_runtime.h>
#include <math.h>

// ---------------------------------------------------------------------------
// VQVAE forward. v13: conv2 = v12 geometry with the spill fixed. v12's
// __launch_bounds__(512,4) acts as min-BLOCKS-per-CU in this toolchain ->
// 8 waves/SIMD -> 64-VGPR clamp -> scratch spill (WRITE_SIZE 16.4->58.5 MB).
// v13 uses (512,2): VGPR cap 128 (kernel needs ~90), LDS 41984 B -> exactly
// 2 blocks/CU on the 512-block grid = 16 waves/CU = 4 waves/SIMD, double
// v10's latency cover with zero spill. Everything else unchanged from v12.
// ---------------------------------------------------------------------------

typedef _Float16 f16x8 __attribute__((ext_vector_type(8)));
typedef float f32x4 __attribute__((ext_vector_type(4)));

#define H1N 16777216        // elements per h1 plane; zero tail after
#define H1PL 16777280       // f16 offset between h1h and h1l planes
#define YTAIL (2048 * 128)  // zero page in Yh/Yl for OOB shifts

// ---------- prep: A-agg (0..127), W-split (128..143), cbT (144..151), misc --
__global__ __launch_bounds__(256) void k_prep(const float* __restrict__ w2,
                                              const float* __restrict__ w1,
                                              const float* __restrict__ wp,
                                              const float* __restrict__ wd,
                                              const float* __restrict__ wd1,
                                              const float* __restrict__ cb,
                                              float* __restrict__ w1t,
                                              float* __restrict__ wpT,
                                              float* __restrict__ wdT,
                                              float* __restrict__ cbT,
                                              _Float16* __restrict__ Ah,
                                              _Float16* __restrict__ Al,
                                              _Float16* __restrict__ Wh,
                                              _Float16* __restrict__ Wl,
                                              _Float16* __restrict__ h1h,
                                              _Float16* __restrict__ h1l) {
  int bx = blockIdx.x, tid = threadIdx.x;
  if (bx < 128) {  // ---- A aggregation, block = co, lanes = ci (writes coalesced)
    __shared__ float wrow[1152];
    int co = bx;
    for (int i = tid; i < 1152; i += 256) wrow[i] = wd1[co * 1152 + i];
    __syncthreads();
    if (tid < 128) {
      int ci = tid;
      float w[9];
#pragma unroll
      for (int t = 0; t < 9; t++) w[t] = wrow[ci * 9 + t];
      float rx[3][5];
#pragma unroll
      for (int ky = 0; ky < 3; ky++) {
        float a0 = w[ky * 3 + 0], a1 = w[ky * 3 + 1], a2 = w[ky * 3 + 2];
        rx[ky][0] = a0; rx[ky][1] = a1 + a2; rx[ky][2] = a0 + a1 + a2;
        rx[ky][3] = a0 + a1; rx[ky][4] = a2;
      }
#pragma unroll
      for (int px = 0; px < 5; px++) {
        float s0 = rx[0][px], s1 = rx[1][px], s2 = rx[2][px];
        float ry[5];
        ry[0] = s0; ry[1] = s1 + s2; ry[2] = s0 + s1 + s2; ry[3] = s0 + s1; ry[4] = s2;
#pragma unroll
        for (int py = 0; py < 5; py++) {
          int pq = py * 5 + px;
          float v = ry[py];
          _Float16 h = (_Float16)v;
          int o = (pq * 128 + co) * 128 + ci;
          Ah[o] = h;
          Al[o] = (_Float16)(v - (float)h);
        }
      }
    }
    return;
  }
  if (bx < 144) {  // ---- W f16-split: 8 co per block, LDS-staged, coalesced RW
    __shared__ float wst[9216];
    int co0 = (bx - 128) * 8;
    for (int i = tid; i < 9216; i += 256) wst[i] = w2[co0 * 1152 + i];
    __syncthreads();
    for (int i = tid; i < 9216; i += 256) {
      int co = i / 1152, r = i - co * 1152;
      int tap = r >> 7, ci = r & 127;
      float v = wst[co * 1152 + ci * 9 + tap];
      _Float16 h = (_Float16)v;
      int o = (tap * 128 + co0 + co) * 128 + ci;
      Wh[o] = h;
      Wl[o] = (_Float16)(v - (float)h);
    }
    return;
  }
  if (bx < 152) {  // ---- cbT tile transpose (64 k x 64 d), padded LDS
    __shared__ float cbs[64 * 65];
    int k0 = (bx - 144) * 64;
    for (int i = tid; i < 4096; i += 256) {
      int k = i >> 6, d = i & 63;
      cbs[k * 65 + d] = cb[(k0 + k) * 64 + d];
    }
    __syncthreads();
    for (int i = tid; i < 4096; i += 256) {
      int d = i >> 6, k = i & 63;
      cbT[d * 512 + k0 + k] = cbs[k * 65 + d];
    }
    return;
  }
  // ---- misc small transposes + h1 zero tails (writes lane-contiguous)
  for (int i = tid; i < 3456; i += 256) {  // w1t[t][co] = w1[co][t]
    int co = i & 127, t = i >> 7;
    w1t[t * 128 + co] = w1[co * 27 + t];
  }
  for (int i = tid; i < 8192; i += 256) {  // wpT[k][d] = wp[d][k]
    int d = i & 63, k = i >> 6;
    wpT[k * 64 + d] = wp[d * 128 + k];
  }
  for (int i = tid; i < 8192; i += 256) {  // wdT[d][co] = wd[co][d]
    int co = i & 127, d = i >> 7;
    wdT[d * 128 + co] = wd[co * 64 + d];
  }
  if (tid < 64) {
    h1h[H1N + tid] = (_Float16)0.f;
    h1l[H1N + tid] = (_Float16)0.f;
  }
}

// ---------- conv1: (32,3,128,128) -> h1 f16-split [g][b][oh][ow][8ci] -------
__global__ __launch_bounds__(256) void k_conv1(const float* __restrict__ x,
                                               const float* __restrict__ w1t,
                                               const float* __restrict__ b1,
                                               _Float16* __restrict__ h1h,
                                               _Float16* __restrict__ h1l) {
  __shared__ float E[3][9][68];
  __shared__ float O[3][9][68];
  int co_t = blockIdx.x, oh_t = blockIdx.y, b = blockIdx.z;
  int oh0 = oh_t * 4;
  int tid = threadIdx.x;
  int wv = __builtin_amdgcn_readfirstlane(tid >> 6);
  int l = tid & 63;
  int coB = co_t * 32 + wv * 8;

  for (int idx = tid; idx < 1728; idx += 256) {
    int p = idx & 63, r = idx >> 6;
    int ci = r / 9, lr = r - ci * 9;
    int ih = 2 * oh0 - 1 + lr;
    float2 v = make_float2(0.f, 0.f);
    if ((unsigned)ih < 128u)
      v = *(const float2*)&x[((b * 3 + ci) * 128 + ih) * 128 + 2 * p];
    E[ci][lr][p] = v.x;
    O[ci][lr][p + 1] = v.y;
  }
  if (tid < 27) {
    int ci = tid / 9, lr = tid - ci * 9;
    O[ci][lr][0] = 0.f;
  }
  __syncthreads();

  int ohl = l >> 4, ow0 = (l & 15) * 4;
  int oh = oh0 + ohl;
  float4 acc[8];
#pragma unroll
  for (int q = 0; q < 8; q++) {
    float bv = b1[coB + q];
    acc[q] = make_float4(bv, bv, bv, bv);
  }
#pragma unroll
  for (int ci = 0; ci < 3; ci++) {
#pragma unroll
    for (int ky = 0; ky < 3; ky++) {
      int lr = 2 * ohl + ky;
      float4 ev = *(float4*)&E[ci][lr][ow0];
      float4 od = *(float4*)&O[ci][lr][ow0];
      float o4 = O[ci][lr][ow0 + 4];
      const float* wr = w1t + (ci * 9 + ky * 3) * 128 + coB;
#pragma unroll
      for (int q = 0; q < 8; q++) {
        float wa = wr[q], wb = wr[128 + q], wc = wr[256 + q];
        acc[q].x = fmaf(wa, od.x, acc[q].x);
        acc[q].x = fmaf(wb, ev.x, acc[q].x);
        acc[q].x = fmaf(wc, od.y, acc[q].x);
        acc[q].y = fmaf(wa, od.y, acc[q].y);
        acc[q].y = fmaf(wb, ev.y, acc[q].y);
        acc[q].y = fmaf(wc, od.z, acc[q].y);
        acc[q].z = fmaf(wa, od.z, acc[q].z);
        acc[q].z = fmaf(wb, ev.z, acc[q].z);
        acc[q].z = fmaf(wc, od.w, acc[q].z);
        acc[q].w = fmaf(wa, od.w, acc[q].w);
        acc[q].w = fmaf(wb, ev.w, acc[q].w);
        acc[q].w = fmaf(wc, o4,   acc[q].w);
      }
    }
  }
  int g = coB >> 3;
  int pbase = ((g * 32 + b) * 64 + oh) * 64;
#pragma unroll
  for (int oi = 0; oi < 4; oi++) {
    f16x8 hv, lv;
#pragma unroll
    for (int q = 0; q < 8; q++) {
      float v = fmaxf(((const float*)&acc[q])[oi], 0.f);
      _Float16 h = (_Float16)v;
      float rem = v - (float)h;
      hv[q] = h;
      lv[q] = (_Float16)rem;
    }
    int base = (pbase + ow0 + oi) * 8;
    *(f16x8*)&h1h[base] = hv;
    *(f16x8*)&h1l[base] = lv;
  }
}

// ---------- conv2: f16-split MFMA; 512 blocks x 8 waves, 2 blocks/CU --------
// grid 512 = (b(32) x ohp(16)); block 512 = 8 waves. wave w: co-group (w&3),
// output row rw=(w>>2) -> oh = ohp*2 + rw. Wave computes 32co x 32px,
// acc[2][2]. LDS B (41.6 KB, single buffer): chunk c =
// ((g*5 + r)*2 + pl)*65 + (ph? 33+u : u), g=ci8-group(4), r=row(5:
// ih=2*oh0-1+r), pl=plane, ph=0: iw=2u-1, ph=1: iw=2u. Stage: 5 full
// 512-thread global_load_lds rounds + 40-chunk masked tail; 2 barriers/step.
// __launch_bounds__(512,2): VGPR cap 128 (no spill); 2 blocks/CU resident.
#define C2_CHUNKS 2600
#define C2_STEP 4194304  // h1 element advance per +32ci step

__global__ __launch_bounds__(512, 2) void k_conv2(const _Float16* __restrict__ h1h,
                                                  const _Float16* __restrict__ Wh,
                                                  const _Float16* __restrict__ Wl,
                                                  const float* __restrict__ b2,
                                                  float* __restrict__ h2) {
  __shared__ _Float16 Bbuf[C2_CHUNKS * 8];  // 41600 B
  int bx = blockIdx.x;
  int b = bx >> 4, ohp = bx & 15;
  int oh0 = ohp * 2;
  int tid = threadIdx.x;
  int w = tid >> 6, l = tid & 63;
  int cw = w & 3, rw = w >> 2;
  int ln = l & 15, quad = l >> 4;
  int coW = cw * 32;
  int kq = quad * 8;

  // ---- precompute staging descriptors: 6 chunks/thread (last partial) ----
  int cursrc[6];
  int adv[6];
#pragma unroll
  for (int k = 0; k < 6; k++) {
    int c = tid + k * 512;
    if (c < C2_CHUNKS) {
      int q = c / 65, rem = c - q * 65;
      int ph = rem >= 33;
      int u = ph ? rem - 33 : rem;
      int pl = q & 1, t = q >> 1;
      int r = t % 5, g = t / 5;
      int iw = ph ? 2 * u : 2 * u - 1;
      int ih = 2 * oh0 - 1 + r;
      bool ok = (ih >= 0) && (iw >= 0) && (iw < 64);
      cursrc[k] = pl * H1PL + (ok ? ((g * 32 + b) * 64 + ih) * 512 + iw * 8 : H1N);
      adv[k] = ok ? C2_STEP : 0;
    } else {
      cursrc[k] = H1N;
      adv[k] = 0;
    }
  }

  f32x4 acc[2][2] = {};  // [cs][sc]
  for (int step = 0; step < 4; step++) {
    if (step) __syncthreads();  // prior compute done reading Bbuf
#pragma unroll
    for (int k = 0; k < 5; k++) {
      __builtin_amdgcn_global_load_lds(
          (const __attribute__((address_space(1))) void*)(h1h + cursrc[k]),
          (__attribute__((address_space(3))) void*)&Bbuf[(tid + k * 512) * 8],
          16, 0, 0);
      cursrc[k] += adv[k];
    }
    if (tid < 40)
      __builtin_amdgcn_global_load_lds(
          (const __attribute__((address_space(1))) void*)(h1h + cursrc[5]),
          (__attribute__((address_space(3))) void*)&Bbuf[(2560 + tid) * 8],
          16, 0, 0);
    cursrc[5] += adv[5];
    __syncthreads();  // drains vmcnt; stage complete

    const int ci0 = step * 32;
#pragma unroll
    for (int ky = 0; ky < 3; ky++) {
#pragma unroll
      for (int kx = 0; kx < 3; kx++) {
        int tap = ky * 3 + kx;
        const int wbase = (tap * 128 + coW + ln) * 128 + ci0 + kq;
        f16x8 Ah0 = *(const f16x8*)&Wh[wbase];
        f16x8 Al0 = *(const f16x8*)&Wl[wbase];
        f16x8 Ah1 = *(const f16x8*)&Wh[wbase + 2048];  // +16 co
        f16x8 Al1 = *(const f16x8*)&Wl[wbase + 2048];
        int r = 2 * rw + ky;
        int base = ((quad * 5 + r) * 2) * 65;
#pragma unroll
        for (int sc = 0; sc < 2; sc++) {
          int owl = sc * 16 + ln;
          int uoff = (kx == 1) ? (33 + owl) : (owl + (kx == 2));
          f16x8 Bh = *(const f16x8*)&Bbuf[(base + uoff) * 8];
          f16x8 Bl = *(const f16x8*)&Bbuf[(base + 65 + uoff) * 8];
          acc[0][sc] = __builtin_amdgcn_mfma_f32_16x16x32_f16(Al0, Bh, acc[0][sc], 0, 0, 0);
          acc[0][sc] = __builtin_amdgcn_mfma_f32_16x16x32_f16(Ah0, Bl, acc[0][sc], 0, 0, 0);
          acc[0][sc] = __builtin_amdgcn_mfma_f32_16x16x32_f16(Ah0, Bh, acc[0][sc], 0, 0, 0);
          acc[1][sc] = __builtin_amdgcn_mfma_f32_16x16x32_f16(Al1, Bh, acc[1][sc], 0, 0, 0);
          acc[1][sc] = __builtin_amdgcn_mfma_f32_16x16x32_f16(Ah1, Bl, acc[1][sc], 0, 0, 0);
          acc[1][sc] = __builtin_amdgcn_mfma_f32_16x16x32_f16(Ah1, Bh, acc[1][sc], 0, 0, 0);
        }
      }
    }
  }
  // epilogue: C row = co (quad*4+reg), col = px (lane&15)
  int oh = oh0 + rw;
#pragma unroll
  for (int cs = 0; cs < 2; cs++)
#pragma unroll
    for (int sc = 0; sc < 2; sc++) {
      int ow = sc * 16 + ln;
#pragma unroll
      for (int r2 = 0; r2 < 4; r2++) {
        int co = coW + cs * 16 + quad * 4 + r2;
        h2[((b * 128 + co) * 32 + oh) * 32 + ow] = fmaxf(acc[cs][sc][r2] + b2[co], 0.f);
      }
    }
}

// ---------- pool(4x4 mean) + proj(1x1,128->64); grid 128 (b x quarter) ------
__global__ __launch_bounds__(256) void k_poolproj(const float* __restrict__ h2,
                                                  const float* __restrict__ wpT,
                                                  const float* __restrict__ pb,
                                                  float* __restrict__ z_e_out,
                                                  float* __restrict__ lossacc) {
  __shared__ float hp[128][16];
  __shared__ float Ws[128][64];
  int bx = blockIdx.x, tid = threadIdx.x;
  int b = bx >> 2, quarter = bx & 3;
  if (bx == 0 && tid == 0) lossacc[0] = 0.f;
  for (int i = tid; i < 8192; i += 256) Ws[i >> 6][i & 63] = wpT[i];
  for (int i = tid; i < 2048; i += 256) {
    int ci = i >> 4, pl = i & 15;
    int pi = quarter * 16 + pl;
    int bi = pi >> 3, bj = pi & 7;
    const float* src = &h2[((b * 128 + ci) * 32 + bi * 4) * 32 + bj * 4];
    float4 r0 = *(const float4*)src;
    float4 r1 = *(const float4*)(src + 32);
    float4 r2 = *(const float4*)(src + 64);
    float4 r3 = *(const float4*)(src + 96);
    float s = r0.x + r0.y + r0.z + r0.w + r1.x + r1.y + r1.z + r1.w +
              r2.x + r2.y + r2.z + r2.w + r3.x + r3.y + r3.z + r3.w;
    hp[ci][pl] = s * 0.0625f;
  }
  __syncthreads();
  int d = tid >> 2, s0 = (tid & 3) * 4;
  float4 acc = make_float4(0.f, 0.f, 0.f, 0.f);
  for (int k = 0; k < 128; k++) {
    float a = Ws[k][d];
    float4 h = *(float4*)&hp[k][s0];
    acc.x = fmaf(a, h.x, acc.x);
    acc.y = fmaf(a, h.y, acc.y);
    acc.z = fmaf(a, h.z, acc.z);
    acc.w = fmaf(a, h.w, acc.w);
  }
  float bv = pb[d];
  float4 r4 = make_float4(acc.x + bv, acc.y + bv, acc.z + bv, acc.w + bv);
  *(float4*)&z_e_out[(b * 64 + d) * 64 + quarter * 16 + s0] = r4;
}

// ---------- VQ argmin + loss + dproj -> Yh/Yl f16 planes; grid 2048 ----------
__global__ __launch_bounds__(64) void k_vqdproj(const float* __restrict__ z_e,
                                                const float* __restrict__ cbT,
                                                const float* __restrict__ cb,
                                                const float* __restrict__ wdT,
                                                const float* __restrict__ db,
                                                float* __restrict__ idx_f,
                                                _Float16* __restrict__ Yh,
                                                _Float16* __restrict__ Yl,
                                                float* __restrict__ loss_acc) {
  __shared__ float zs[64];
  int n = blockIdx.x, lane = threadIdx.x;
  int b = n >> 6, pi = n & 63;
  zs[lane] = z_e[(b * 64 + lane) * 64 + pi];
  if (n == 0) {  // zero tail page for shifted reads in k_dec
    Yh[YTAIL + lane] = (_Float16)0.f;
    Yh[YTAIL + 64 + lane] = (_Float16)0.f;
    Yl[YTAIL + lane] = (_Float16)0.f;
    Yl[YTAIL + 64 + lane] = (_Float16)0.f;
  }
  __syncthreads();
  double best = 1e300;
  int bi = 0;
#pragma unroll 2
  for (int j = 0; j < 8; j++) {
    int k = j * 64 + lane;
    double a0 = 0.0, a1 = 0.0, a2 = 0.0, a3 = 0.0;
#pragma unroll 4
    for (int d = 0; d < 64; d += 4) {
      double f0 = (double)zs[d] - (double)cbT[d * 512 + k];
      double f1 = (double)zs[d + 1] - (double)cbT[(d + 1) * 512 + k];
      double f2 = (double)zs[d + 2] - (double)cbT[(d + 2) * 512 + k];
      double f3 = (double)zs[d + 3] - (double)cbT[(d + 3) * 512 + k];
      a0 = fma(f0, f0, a0);
      a1 = fma(f1, f1, a1);
      a2 = fma(f2, f2, a2);
      a3 = fma(f3, f3, a3);
    }
    double acc = (a0 + a1) + (a2 + a3);
    if (acc < best) { best = acc; bi = k; }
  }
  for (int m = 1; m < 64; m <<= 1) {
    double ob = __shfl_xor(best, m, 64);
    int oi = __shfl_xor(bi, m, 64);
    if (ob < best || (ob == best && oi < bi)) { best = ob; bi = oi; }
  }
  float zq_l = cb[bi * 64 + lane];
  float e = zq_l - zs[lane];
  float sq = e * e;
  for (int m = 1; m < 64; m <<= 1) sq += __shfl_xor(sq, m, 64);
  if (lane == 0) {
    idx_f[n] = (float)bi;
    atomicAdd(loss_acc, sq);
  }
  __syncthreads();
  zs[lane] = zq_l;
  __syncthreads();
  float a0 = db[lane], a1 = db[lane + 64];
#pragma unroll 4
  for (int d = 0; d < 64; d++) {
    float z = zs[d];
    a0 = fmaf(wdT[d * 128 + lane], z, a0);
    a1 = fmaf(wdT[d * 128 + lane + 64], z, a1);
  }
  float y0 = fmaxf(a0, 0.f), y1 = fmaxf(a1, 0.f);
  _Float16 h0 = (_Float16)y0, h1v = (_Float16)y1;
  Yh[n * 128 + lane] = h0;
  Yh[n * 128 + lane + 64] = h1v;
  Yl[n * 128 + lane] = (_Float16)(y0 - (float)h0);
  Yl[n * 128 + lane + 64] = (_Float16)(y1 - (float)h1v);
}

// ---------- dec: f16-split MFMA, G[pq][n][co] = A_pq * Yshift ----------
__global__ __launch_bounds__(256) void k_dec(const _Float16* __restrict__ Yh,
                                             const _Float16* __restrict__ Yl,
                                             const _Float16* __restrict__ Ah,
                                             const _Float16* __restrict__ Al,
                                             float* __restrict__ G) {
  int bxx = blockIdx.x;
  int pq = bxx >> 6, n_t = bxx & 63;
  int w = threadIdx.x >> 6, l = threadIdx.x & 63;
  int ln = l & 15, quad = l >> 4;
  int coW = w * 32;
  int nB = n_t * 32;
  int py = pq / 5, px = pq - py * 5;
  int dy = (py == 0) ? -1 : ((py == 4) ? 1 : 0);
  int dx = (px == 0) ? -1 : ((px == 4) ? 1 : 0);
  int src[2];
#pragma unroll
  for (int s = 0; s < 2; s++) {
    int n = nB + s * 16 + ln;
    int bb = n >> 6, s6 = n & 63;
    int sy = (s6 >> 3) + dy, sx = (s6 & 7) + dx;
    bool ok = ((unsigned)sy < 8u) && ((unsigned)sx < 8u);
    src[s] = ok ? ((bb * 64 + sy * 8 + sx) * 128) : YTAIL;
  }
  int kq = quad * 8;
  f32x4 acc[2][2] = {};
#pragma unroll 2
  for (int ci0 = 0; ci0 < 128; ci0 += 32) {
    const int wbase = (pq * 128 + coW + ln) * 128 + ci0 + kq;
    f16x8 Ah0 = *(const f16x8*)&Ah[wbase];
    f16x8 Al0 = *(const f16x8*)&Al[wbase];
    f16x8 Ah1 = *(const f16x8*)&Ah[wbase + 2048];
    f16x8 Al1 = *(const f16x8*)&Al[wbase + 2048];
    f16x8 Bh[2], Bl[2];
#pragma unroll
    for (int s = 0; s < 2; s++) {
      Bh[s] = *(const f16x8*)&Yh[src[s] + ci0 + kq];
      Bl[s] = *(const f16x8*)&Yl[src[s] + ci0 + kq];
    }
#pragma unroll
    for (int cs = 0; cs < 2; cs++) {
      f16x8 ah = cs ? Ah1 : Ah0;
      f16x8 al = cs ? Al1 : Al0;
#pragma unroll
      for (int s = 0; s < 2; s++) {
        acc[cs][s] = __builtin_amdgcn_mfma_f32_16x16x32_f16(al, Bh[s], acc[cs][s], 0, 0, 0);
        acc[cs][s] = __builtin_amdgcn_mfma_f32_16x16x32_f16(ah, Bl[s], acc[cs][s], 0, 0, 0);
        acc[cs][s] = __builtin_amdgcn_mfma_f32_16x16x32_f16(ah, Bh[s], acc[cs][s], 0, 0, 0);
      }
    }
  }
#pragma unroll
  for (int cs = 0; cs < 2; cs++)
#pragma unroll
    for (int s = 0; s < 2; s++) {
      int site = nB + s * 16 + ln;
      float4 g = make_float4(acc[cs][s][0], acc[cs][s][1], acc[cs][s][2], acc[cs][s][3]);
      *(float4*)&G[(pq * 2048 + site) * 128 + coW + cs * 16 + quad * 4] = g;
    }
}

// ---------- out: combine G per class, bias+relu, 1x1 conv to 3ch, splat ------
__global__ __launch_bounds__(256) void k_out(const float* __restrict__ G,
                                             const float* __restrict__ bc1,
                                             const float* __restrict__ w3,
                                             const float* __restrict__ b3,
                                             float* __restrict__ xhat,
                                             const float* __restrict__ loss_acc,
                                             float* __restrict__ out_loss) {
  __shared__ float Tb[9][128];
  __shared__ float part[9][3][8];
  __shared__ float vals[9][3];
  int bj = blockIdx.x, bi = blockIdx.y, b = blockIdx.z;
  int s = bi * 8 + bj;
  int n = b * 64 + s;
  int tid = threadIdx.x;
  if (bj == 0 && bi == 0 && b == 0 && tid == 0)
    out_loss[0] = loss_acc[0] * 1.25f / 131072.0f;
  int co = tid & 127, h = tid >> 7;
  const int rset[3][2] = {{0, 1}, {2, 2}, {3, 4}};
  const int rcnt[3] = {2, 1, 2};
  for (int cls = h; cls < 9; cls += 2) {
    int r = cls / 3, c = cls - r * 3;
    float sum = bc1[co];
    for (int iy = 0; iy < rcnt[r]; iy++) {
      int py = rset[r][iy];
      for (int ix = 0; ix < rcnt[c]; ix++) {
        int px = rset[c][ix];
        sum += G[((py * 5 + px) * 2048 + n) * 128 + co];
      }
    }
    Tb[cls][co] = fmaxf(sum, 0.f);
  }
  __syncthreads();
  if (tid < 216) {
    int cls = tid / 24, rem = tid - cls * 24;
    int cc = rem >> 3, seg = rem & 7;
    float ss = 0.f;
#pragma unroll
    for (int d = 0; d < 16; d++) ss = fmaf(w3[cc * 128 + seg * 16 + d], Tb[cls][seg * 16 + d], ss);
    part[cls][cc][seg] = ss;
  }
  __syncthreads();
  if (tid < 27) {
    int cls = tid / 3, cc = tid - cls * 3;
    float ss = b3[cc];
#pragma unroll
    for (int seg = 0; seg < 8; seg++) ss += part[cls][cc][seg];
    vals[cls][cc] = ss;
  }
  __syncthreads();
  for (int i = tid; i < 768; i += 256) {
    int cc = i >> 8, p = i & 255;
    int ry = p >> 4, rx = p & 15;
    int rcls = (ry == 0) ? 0 : ((ry == 15) ? 2 : 1);
    int ccls = (rx == 0) ? 0 : ((rx == 15) ? 2 : 1);
    xhat[((b * 3 + cc) * 128 + bi * 16 + ry) * 128 + bj * 16 + rx] =
        vals[rcls * 3 + ccls][cc];
  }
}

extern "C" void kernel_launch(void* const* d_in, const int* in_sizes, int n_in,
                              void* d_out, int out_size, void* d_ws, size_t ws_size,
                              hipStream_t stream) {
  const float* x   = (const float*)d_in[0];
  const float* w1  = (const float*)d_in[1];
  const float* b1  = (const float*)d_in[2];
  const float* w2  = (const float*)d_in[3];
  const float* b2  = (const float*)d_in[4];
  const float* wp  = (const float*)d_in[5];
  const float* pb  = (const float*)d_in[6];
  const float* cb  = (const float*)d_in[7];
  const float* wd  = (const float*)d_in[8];
  const float* db  = (const float*)d_in[9];
  const float* wc1 = (const float*)d_in[10];
  const float* bc1 = (const float*)d_in[11];
  const float* wc2 = (const float*)d_in[12];
  const float* bc2 = (const float*)d_in[13];
  float* out = (float*)d_out;
  float* ws  = (float*)d_ws;

  // workspace (float offsets):
  _Float16* h1h = (_Float16*)(ws);             // [0, 8388640)  (h1l = h1h + H1PL)
  _Float16* h1l = (_Float16*)(ws + 8388640);   // [8388640, 16777280)
  float* h2     = ws + 16777280;               // 4194304
  _Float16* Wh  = (_Float16*)(ws + 20971584);  // 73728 fl
  _Float16* Wl  = (_Float16*)(ws + 21045312);  // 73728 fl
  float* w1t    = ws + 21119040;               // 3456
  float* wpT    = ws + 21122496;               // 8192
  float* wdT    = ws + 21130688;               // 8192
  float* cbT    = ws + 21138880;               // 32768
  _Float16* Ahd = (_Float16*)(ws + 21171648);  // 204800 fl
  _Float16* Ald = (_Float16*)(ws + 21376448);  // 204800 fl -> end 21581248
  // overlays inside dead h1h/h1l region (valid after conv2):
  float* G       = ws;                         // [0, 6553600)
  _Float16* Yh   = (_Float16*)(ws + 6553600);  // 131136 fl (2049*128 f16)
  _Float16* Yl   = (_Float16*)(ws + 6684736);  // 131136 fl
  float* lossacc = ws + 6815872;               // 1

  float* o_xhat = out;
  float* o_idx  = out + 1572864;
  float* o_loss = out + 1574912;
  float* o_ze   = out + 1574913;

  k_prep<<<dim3(153), 256, 0, stream>>>(w2, w1, wp, wd, wc1, cb,
                                        w1t, wpT, wdT, cbT, Ahd, Ald, Wh, Wl, h1h, h1l);
  k_conv1<<<dim3(4, 16, 32), 256, 0, stream>>>(x, w1t, b1, h1h, h1l);
  k_conv2<<<dim3(512), 512, 0, stream>>>(h1h, Wh, Wl, b2, h2);
  k_poolproj<<<dim3(128), 256, 0, stream>>>(h2, wpT, pb, o_ze, lossacc);
  k_vqdproj<<<dim3(2048), 64, 0, stream>>>(o_ze, cbT, cb, wdT, db, o_idx, Yh, Yl, lossacc);
  k_dec<<<dim3(1600), 256, 0, stream>>>(Yh, Yl, Ahd, Ald, G);
  k_out<<<dim3(8, 8, 32), 256, 0, stream>>>(G, bc1, wc2, bc2, o_xhat, lossacc, o_loss);
}

// Round 5
// 262.995 us; speedup vs baseline: 1.2516x; 1.1786x over previous
//
#include <hip/hip_runtime.h>
#include <math.h>

// ---------------------------------------------------------------------------
// VQVAE forward. v14: drop the activation low plane (h1l) and the Ah*Bl MFMA
// term in conv2 (B becomes f16-rounded; weights stay f16-split, error
// ~3.4e-4 << tolerance). conv1 writes halve (67->33.5 MB), conv2 stages
// halve (LDS dbuf 149.8->74.9 KB, ds_reads 72->36/step) and MFMA drops to
// 2/3 (144/wave/step). conv2 keeps the v10 structure (best measured:
// 256 blocks x 512 thr, 4-row outputs, 9-row act tile, gload_lds dbuf,
// 1 barrier/step) -- v11 (reg-hoist) spilled, v12 (launch-bounds) spilled,
// v13 (2x occupancy) refuted TLP as the lever. k_dec/Yl untouched.
// ---------------------------------------------------------------------------

typedef _Float16 f16x8 __attribute__((ext_vector_type(8)));
typedef float f32x4 __attribute__((ext_vector_type(4)));

#define H1N 16777216        // elements in h1 plane; zero tail after
#define YTAIL (2048 * 128)  // zero page in Yh/Yl for OOB shifts

// ---------- prep: A-agg (0..127), W-split (128..143), cbT (144..151), misc --
__global__ __launch_bounds__(256) void k_prep(const float* __restrict__ w2,
                                              const float* __restrict__ w1,
                                              const float* __restrict__ wp,
                                              const float* __restrict__ wd,
                                              const float* __restrict__ wd1,
                                              const float* __restrict__ cb,
                                              float* __restrict__ w1t,
                                              float* __restrict__ wpT,
                                              float* __restrict__ wdT,
                                              float* __restrict__ cbT,
                                              _Float16* __restrict__ Ah,
                                              _Float16* __restrict__ Al,
                                              _Float16* __restrict__ Wh,
                                              _Float16* __restrict__ Wl,
                                              _Float16* __restrict__ h1h) {
  int bx = blockIdx.x, tid = threadIdx.x;
  if (bx < 128) {  // ---- A aggregation, block = co, lanes = ci (writes coalesced)
    __shared__ float wrow[1152];
    int co = bx;
    for (int i = tid; i < 1152; i += 256) wrow[i] = wd1[co * 1152 + i];
    __syncthreads();
    if (tid < 128) {
      int ci = tid;
      float w[9];
#pragma unroll
      for (int t = 0; t < 9; t++) w[t] = wrow[ci * 9 + t];
      float rx[3][5];
#pragma unroll
      for (int ky = 0; ky < 3; ky++) {
        float a0 = w[ky * 3 + 0], a1 = w[ky * 3 + 1], a2 = w[ky * 3 + 2];
        rx[ky][0] = a0; rx[ky][1] = a1 + a2; rx[ky][2] = a0 + a1 + a2;
        rx[ky][3] = a0 + a1; rx[ky][4] = a2;
      }
#pragma unroll
      for (int px = 0; px < 5; px++) {
        float s0 = rx[0][px], s1 = rx[1][px], s2 = rx[2][px];
        float ry[5];
        ry[0] = s0; ry[1] = s1 + s2; ry[2] = s0 + s1 + s2; ry[3] = s0 + s1; ry[4] = s2;
#pragma unroll
        for (int py = 0; py < 5; py++) {
          int pq = py * 5 + px;
          float v = ry[py];
          _Float16 h = (_Float16)v;
          int o = (pq * 128 + co) * 128 + ci;
          Ah[o] = h;
          Al[o] = (_Float16)(v - (float)h);
        }
      }
    }
    return;
  }
  if (bx < 144) {  // ---- W f16-split: 8 co per block, LDS-staged, coalesced RW
    __shared__ float wst[9216];
    int co0 = (bx - 128) * 8;
    for (int i = tid; i < 9216; i += 256) wst[i] = w2[co0 * 1152 + i];
    __syncthreads();
    for (int i = tid; i < 9216; i += 256) {
      int co = i / 1152, r = i - co * 1152;
      int tap = r >> 7, ci = r & 127;
      float v = wst[co * 1152 + ci * 9 + tap];
      _Float16 h = (_Float16)v;
      int o = (tap * 128 + co0 + co) * 128 + ci;
      Wh[o] = h;
      Wl[o] = (_Float16)(v - (float)h);
    }
    return;
  }
  if (bx < 152) {  // ---- cbT tile transpose (64 k x 64 d), padded LDS
    __shared__ float cbs[64 * 65];
    int k0 = (bx - 144) * 64;
    for (int i = tid; i < 4096; i += 256) {
      int k = i >> 6, d = i & 63;
      cbs[k * 65 + d] = cb[(k0 + k) * 64 + d];
    }
    __syncthreads();
    for (int i = tid; i < 4096; i += 256) {
      int d = i >> 6, k = i & 63;
      cbT[d * 512 + k0 + k] = cbs[k * 65 + d];
    }
    return;
  }
  // ---- misc small transposes + h1 zero tail (writes lane-contiguous)
  for (int i = tid; i < 3456; i += 256) {  // w1t[t][co] = w1[co][t]
    int co = i & 127, t = i >> 7;
    w1t[t * 128 + co] = w1[co * 27 + t];
  }
  for (int i = tid; i < 8192; i += 256) {  // wpT[k][d] = wp[d][k]
    int d = i & 63, k = i >> 6;
    wpT[k * 64 + d] = wp[d * 128 + k];
  }
  for (int i = tid; i < 8192; i += 256) {  // wdT[d][co] = wd[co][d]
    int co = i & 127, d = i >> 7;
    wdT[d * 128 + co] = wd[co * 64 + d];
  }
  if (tid < 64) h1h[H1N + tid] = (_Float16)0.f;
}

// ---------- conv1: (32,3,128,128) -> h1 f16 [g][b][oh][ow][8ci] -------------
__global__ __launch_bounds__(256) void k_conv1(const float* __restrict__ x,
                                               const float* __restrict__ w1t,
                                               const float* __restrict__ b1,
                                               _Float16* __restrict__ h1h) {
  __shared__ float E[3][9][68];
  __shared__ float O[3][9][68];
  int co_t = blockIdx.x, oh_t = blockIdx.y, b = blockIdx.z;
  int oh0 = oh_t * 4;
  int tid = threadIdx.x;
  int wv = __builtin_amdgcn_readfirstlane(tid >> 6);
  int l = tid & 63;
  int coB = co_t * 32 + wv * 8;

  for (int idx = tid; idx < 1728; idx += 256) {
    int p = idx & 63, r = idx >> 6;
    int ci = r / 9, lr = r - ci * 9;
    int ih = 2 * oh0 - 1 + lr;
    float2 v = make_float2(0.f, 0.f);
    if ((unsigned)ih < 128u)
      v = *(const float2*)&x[((b * 3 + ci) * 128 + ih) * 128 + 2 * p];
    E[ci][lr][p] = v.x;
    O[ci][lr][p + 1] = v.y;
  }
  if (tid < 27) {
    int ci = tid / 9, lr = tid - ci * 9;
    O[ci][lr][0] = 0.f;
  }
  __syncthreads();

  int ohl = l >> 4, ow0 = (l & 15) * 4;
  int oh = oh0 + ohl;
  float4 acc[8];
#pragma unroll
  for (int q = 0; q < 8; q++) {
    float bv = b1[coB + q];
    acc[q] = make_float4(bv, bv, bv, bv);
  }
#pragma unroll
  for (int ci = 0; ci < 3; ci++) {
#pragma unroll
    for (int ky = 0; ky < 3; ky++) {
      int lr = 2 * ohl + ky;
      float4 ev = *(float4*)&E[ci][lr][ow0];
      float4 od = *(float4*)&O[ci][lr][ow0];
      float o4 = O[ci][lr][ow0 + 4];
      const float* wr = w1t + (ci * 9 + ky * 3) * 128 + coB;
#pragma unroll
      for (int q = 0; q < 8; q++) {
        float wa = wr[q], wb = wr[128 + q], wc = wr[256 + q];
        acc[q].x = fmaf(wa, od.x, acc[q].x);
        acc[q].x = fmaf(wb, ev.x, acc[q].x);
        acc[q].x = fmaf(wc, od.y, acc[q].x);
        acc[q].y = fmaf(wa, od.y, acc[q].y);
        acc[q].y = fmaf(wb, ev.y, acc[q].y);
        acc[q].y = fmaf(wc, od.z, acc[q].y);
        acc[q].z = fmaf(wa, od.z, acc[q].z);
        acc[q].z = fmaf(wb, ev.z, acc[q].z);
        acc[q].z = fmaf(wc, od.w, acc[q].z);
        acc[q].w = fmaf(wa, od.w, acc[q].w);
        acc[q].w = fmaf(wb, ev.w, acc[q].w);
        acc[q].w = fmaf(wc, o4,   acc[q].w);
      }
    }
  }
  int g = coB >> 3;
  int pbase = ((g * 32 + b) * 64 + oh) * 64;
#pragma unroll
  for (int oi = 0; oi < 4; oi++) {
    f16x8 hv;
#pragma unroll
    for (int q = 0; q < 8; q++)
      hv[q] = (_Float16)fmaxf(((const float*)&acc[q])[oi], 0.f);
    *(f16x8*)&h1h[(pbase + ow0 + oi) * 8] = hv;
  }
}

// ---------- conv2: 2-term split MFMA (Al*Bh + Ah*Bh), v10 structure ---------
// grid 256 = (b(32) x ohq(8)); block 512 = 8 waves. wave w: co-group (w&3),
// row-group rw=(w>>2) -> rows oh0+2*rw..+1. LDS B (37.44 KB/buffer, dbuf):
// chunk c = (g*9 + r)*65 + (ph? 33+u : u), g=ci8-group(4), r=row(9:
// ih=2*oh0-1+r), ph=0: iw=2u-1, ph=1: iw=2u. Stage: 4 full 512-thread
// global_load_lds rounds + 292 masked tail; issue stage(nxt) -> compute(cur)
// -> one __syncthreads per step.
#define C2_CHUNKS 2340
#define C2_BUF (C2_CHUNKS * 8)   // f16 elems per buffer
#define C2_LDS (2 * C2_BUF * 2)  // bytes = 74880
#define C2_STEP 4194304          // h1 element advance per +32ci step

__global__ __launch_bounds__(512, 2) void k_conv2(const _Float16* __restrict__ h1h,
                                                  const _Float16* __restrict__ Wh,
                                                  const _Float16* __restrict__ Wl,
                                                  const float* __restrict__ b2,
                                                  float* __restrict__ h2) {
  extern __shared__ _Float16 Bbuf[];
  int bx = blockIdx.x;
  int b = bx >> 3, ohq = bx & 7;
  int oh0 = ohq * 4;
  int tid = threadIdx.x;
  int w = tid >> 6, l = tid & 63;
  int cw = w & 3, rw = w >> 2;
  int ln = l & 15, quad = l >> 4;
  int coW = cw * 32;
  int kq = quad * 8;

  // ---- staging descriptors: 5 chunks/thread (last partial, tid<292) ----
  int cursrc[5];
  int adv[5];
#pragma unroll
  for (int k = 0; k < 5; k++) {
    int c = (k < 4) ? (tid + k * 512) : (2048 + tid);
    if (c < C2_CHUNKS) {
      int q = c / 65, rem = c - q * 65;
      int ph = rem >= 33;
      int u = ph ? rem - 33 : rem;
      int r = q % 9, g = q / 9;
      int iw = ph ? 2 * u : 2 * u - 1;
      int ih = 2 * oh0 - 1 + r;
      bool ok = (ih >= 0) && (iw >= 0) && (iw < 64);
      cursrc[k] = ok ? ((g * 32 + b) * 64 + ih) * 512 + iw * 8 : H1N;
      adv[k] = ok ? C2_STEP : 0;
    } else {
      cursrc[k] = H1N;
      adv[k] = 0;
    }
  }

#define C2_STAGE(DST)                                                          \
  {                                                                            \
    _Pragma("unroll") for (int k = 0; k < 4; k++) {                            \
      __builtin_amdgcn_global_load_lds(                                        \
          (const __attribute__((address_space(1))) void*)(h1h + cursrc[k]),    \
          (__attribute__((address_space(3))) void*)&Bbuf[(DST) +               \
                                                         (tid + k * 512) * 8], \
          16, 0, 0);                                                           \
      cursrc[k] += adv[k];                                                     \
    }                                                                          \
    if (tid < 292) {                                                           \
      __builtin_amdgcn_global_load_lds(                                        \
          (const __attribute__((address_space(1))) void*)(h1h + cursrc[4]),    \
          (__attribute__((address_space(3))) void*)&Bbuf[(DST) +               \
                                                         (2048 + tid) * 8],    \
          16, 0, 0);                                                           \
    }                                                                          \
    cursrc[4] += adv[4];                                                       \
  }

  int curoff = 0;
  C2_STAGE(0);      // prologue: stage K-step 0 into buffer 0
  __syncthreads();  // drain + barrier

  f32x4 acc[2][4] = {};  // [cs][s]  s = (row-in-pair<<1)|col-half
  for (int step = 0; step < 4; step++) {
    int nxt = curoff ^ C2_BUF;
    if (step < 3) C2_STAGE(nxt);  // issue next K-step's loads
    const int ci0 = step * 32;
#pragma unroll
    for (int ky = 0; ky < 3; ky++) {
#pragma unroll
      for (int kx = 0; kx < 3; kx++) {
        int tap = ky * 3 + kx;
        const int wbase = (tap * 128 + coW + ln) * 128 + ci0 + kq;
        f16x8 Ah0 = *(const f16x8*)&Wh[wbase];
        f16x8 Al0 = *(const f16x8*)&Wl[wbase];
        f16x8 Ah1 = *(const f16x8*)&Wh[wbase + 2048];  // +16 co
        f16x8 Al1 = *(const f16x8*)&Wl[wbase + 2048];
#pragma unroll
        for (int s = 0; s < 4; s++) {
          int owl = (s & 1) * 16 + ln;
          int r = 4 * rw + 2 * (s >> 1) + ky;
          int base = (quad * 9 + r) * 65;
          int uoff = (kx == 1) ? (33 + owl) : (owl + (kx == 2));
          f16x8 Bh = *(const f16x8*)&Bbuf[curoff + (base + uoff) * 8];
          acc[0][s] = __builtin_amdgcn_mfma_f32_16x16x32_f16(Al0, Bh, acc[0][s], 0, 0, 0);
          acc[0][s] = __builtin_amdgcn_mfma_f32_16x16x32_f16(Ah0, Bh, acc[0][s], 0, 0, 0);
          acc[1][s] = __builtin_amdgcn_mfma_f32_16x16x32_f16(Al1, Bh, acc[1][s], 0, 0, 0);
          acc[1][s] = __builtin_amdgcn_mfma_f32_16x16x32_f16(Ah1, Bh, acc[1][s], 0, 0, 0);
        }
      }
    }
    __syncthreads();  // loads into nxt done; all done reading cur
    curoff = nxt;
  }
  // epilogue: C row = co (quad*4+reg), col = px (lane&15)
#pragma unroll
  for (int cs = 0; cs < 2; cs++)
#pragma unroll
    for (int s = 0; s < 4; s++) {
      int oh = oh0 + 2 * rw + (s >> 1);
      int ow = (s & 1) * 16 + ln;
#pragma unroll
      for (int r = 0; r < 4; r++) {
        int co = coW + cs * 16 + quad * 4 + r;
        h2[((b * 128 + co) * 32 + oh) * 32 + ow] = fmaxf(acc[cs][s][r] + b2[co], 0.f);
      }
    }
#undef C2_STAGE
}

// ---------- pool(4x4 mean) + proj(1x1,128->64); grid 128 (b x quarter) ------
__global__ __launch_bounds__(256) void k_poolproj(const float* __restrict__ h2,
                                                  const float* __restrict__ wpT,
                                                  const float* __restrict__ pb,
                                                  float* __restrict__ z_e_out,
                                                  float* __restrict__ lossacc) {
  __shared__ float hp[128][16];
  __shared__ float Ws[128][64];
  int bx = blockIdx.x, tid = threadIdx.x;
  int b = bx >> 2, quarter = bx & 3;
  if (bx == 0 && tid == 0) lossacc[0] = 0.f;
  for (int i = tid; i < 8192; i += 256) Ws[i >> 6][i & 63] = wpT[i];
  for (int i = tid; i < 2048; i += 256) {
    int ci = i >> 4, pl = i & 15;
    int pi = quarter * 16 + pl;
    int bi = pi >> 3, bj = pi & 7;
    const float* src = &h2[((b * 128 + ci) * 32 + bi * 4) * 32 + bj * 4];
    float4 r0 = *(const float4*)src;
    float4 r1 = *(const float4*)(src + 32);
    float4 r2 = *(const float4*)(src + 64);
    float4 r3 = *(const float4*)(src + 96);
    float s = r0.x + r0.y + r0.z + r0.w + r1.x + r1.y + r1.z + r1.w +
              r2.x + r2.y + r2.z + r2.w + r3.x + r3.y + r3.z + r3.w;
    hp[ci][pl] = s * 0.0625f;
  }
  __syncthreads();
  int d = tid >> 2, s0 = (tid & 3) * 4;
  float4 acc = make_float4(0.f, 0.f, 0.f, 0.f);
  for (int k = 0; k < 128; k++) {
    float a = Ws[k][d];
    float4 h = *(float4*)&hp[k][s0];
    acc.x = fmaf(a, h.x, acc.x);
    acc.y = fmaf(a, h.y, acc.y);
    acc.z = fmaf(a, h.z, acc.z);
    acc.w = fmaf(a, h.w, acc.w);
  }
  float bv = pb[d];
  float4 r4 = make_float4(acc.x + bv, acc.y + bv, acc.z + bv, acc.w + bv);
  *(float4*)&z_e_out[(b * 64 + d) * 64 + quarter * 16 + s0] = r4;
}

// ---------- VQ argmin + loss + dproj -> Yh/Yl f16 planes; grid 2048 ----------
__global__ __launch_bounds__(64) void k_vqdproj(const float* __restrict__ z_e,
                                                const float* __restrict__ cbT,
                                                const float* __restrict__ cb,
                                                const float* __restrict__ wdT,
                                                const float* __restrict__ db,
                                                float* __restrict__ idx_f,
                                                _Float16* __restrict__ Yh,
                                                _Float16* __restrict__ Yl,
                                                float* __restrict__ loss_acc) {
  __shared__ float zs[64];
  int n = blockIdx.x, lane = threadIdx.x;
  int b = n >> 6, pi = n & 63;
  zs[lane] = z_e[(b * 64 + lane) * 64 + pi];
  if (n == 0) {  // zero tail page for shifted reads in k_dec
    Yh[YTAIL + lane] = (_Float16)0.f;
    Yh[YTAIL + 64 + lane] = (_Float16)0.f;
    Yl[YTAIL + lane] = (_Float16)0.f;
    Yl[YTAIL + 64 + lane] = (_Float16)0.f;
  }
  __syncthreads();
  double best = 1e300;
  int bi = 0;
#pragma unroll 2
  for (int j = 0; j < 8; j++) {
    int k = j * 64 + lane;
    double a0 = 0.0, a1 = 0.0, a2 = 0.0, a3 = 0.0;
#pragma unroll 4
    for (int d = 0; d < 64; d += 4) {
      double f0 = (double)zs[d] - (double)cbT[d * 512 + k];
      double f1 = (double)zs[d + 1] - (double)cbT[(d + 1) * 512 + k];
      double f2 = (double)zs[d + 2] - (double)cbT[(d + 2) * 512 + k];
      double f3 = (double)zs[d + 3] - (double)cbT[(d + 3) * 512 + k];
      a0 = fma(f0, f0, a0);
      a1 = fma(f1, f1, a1);
      a2 = fma(f2, f2, a2);
      a3 = fma(f3, f3, a3);
    }
    double acc = (a0 + a1) + (a2 + a3);
    if (acc < best) { best = acc; bi = k; }
  }
  for (int m = 1; m < 64; m <<= 1) {
    double ob = __shfl_xor(best, m, 64);
    int oi = __shfl_xor(bi, m, 64);
    if (ob < best || (ob == best && oi < bi)) { best = ob; bi = oi; }
  }
  float zq_l = cb[bi * 64 + lane];
  float e = zq_l - zs[lane];
  float sq = e * e;
  for (int m = 1; m < 64; m <<= 1) sq += __shfl_xor(sq, m, 64);
  if (lane == 0) {
    idx_f[n] = (float)bi;
    atomicAdd(loss_acc, sq);
  }
  __syncthreads();
  zs[lane] = zq_l;
  __syncthreads();
  float a0 = db[lane], a1 = db[lane + 64];
#pragma unroll 4
  for (int d = 0; d < 64; d++) {
    float z = zs[d];
    a0 = fmaf(wdT[d * 128 + lane], z, a0);
    a1 = fmaf(wdT[d * 128 + lane + 64], z, a1);
  }
  float y0 = fmaxf(a0, 0.f), y1 = fmaxf(a1, 0.f);
  _Float16 h0 = (_Float16)y0, h1v = (_Float16)y1;
  Yh[n * 128 + lane] = h0;
  Yh[n * 128 + lane + 64] = h1v;
  Yl[n * 128 + lane] = (_Float16)(y0 - (float)h0);
  Yl[n * 128 + lane + 64] = (_Float16)(y1 - (float)h1v);
}

// ---------- dec: f16-split MFMA, G[pq][n][co] = A_pq * Yshift ----------
__global__ __launch_bounds__(256) void k_dec(const _Float16* __restrict__ Yh,
                                             const _Float16* __restrict__ Yl,
                                             const _Float16* __restrict__ Ah,
                                             const _Float16* __restrict__ Al,
                                             float* __restrict__ G) {
  int bxx = blockIdx.x;
  int pq = bxx >> 6, n_t = bxx & 63;
  int w = threadIdx.x >> 6, l = threadIdx.x & 63;
  int ln = l & 15, quad = l >> 4;
  int coW = w * 32;
  int nB = n_t * 32;
  int py = pq / 5, px = pq - py * 5;
  int dy = (py == 0) ? -1 : ((py == 4) ? 1 : 0);
  int dx = (px == 0) ? -1 : ((px == 4) ? 1 : 0);
  int src[2];
#pragma unroll
  for (int s = 0; s < 2; s++) {
    int n = nB + s * 16 + ln;
    int bb = n >> 6, s6 = n & 63;
    int sy = (s6 >> 3) + dy, sx = (s6 & 7) + dx;
    bool ok = ((unsigned)sy < 8u) && ((unsigned)sx < 8u);
    src[s] = ok ? ((bb * 64 + sy * 8 + sx) * 128) : YTAIL;
  }
  int kq = quad * 8;
  f32x4 acc[2][2] = {};
#pragma unroll 2
  for (int ci0 = 0; ci0 < 128; ci0 += 32) {
    const int wbase = (pq * 128 + coW + ln) * 128 + ci0 + kq;
    f16x8 Ah0 = *(const f16x8*)&Ah[wbase];
    f16x8 Al0 = *(const f16x8*)&Al[wbase];
    f16x8 Ah1 = *(const f16x8*)&Ah[wbase + 2048];
    f16x8 Al1 = *(const f16x8*)&Al[wbase + 2048];
    f16x8 Bh[2], Bl[2];
#pragma unroll
    for (int s = 0; s < 2; s++) {
      Bh[s] = *(const f16x8*)&Yh[src[s] + ci0 + kq];
      Bl[s] = *(const f16x8*)&Yl[src[s] + ci0 + kq];
    }
#pragma unroll
    for (int cs = 0; cs < 2; cs++) {
      f16x8 ah = cs ? Ah1 : Ah0;
      f16x8 al = cs ? Al1 : Al0;
#pragma unroll
      for (int s = 0; s < 2; s++) {
        acc[cs][s] = __builtin_amdgcn_mfma_f32_16x16x32_f16(al, Bh[s], acc[cs][s], 0, 0, 0);
        acc[cs][s] = __builtin_amdgcn_mfma_f32_16x16x32_f16(ah, Bl[s], acc[cs][s], 0, 0, 0);
        acc[cs][s] = __builtin_amdgcn_mfma_f32_16x16x32_f16(ah, Bh[s], acc[cs][s], 0, 0, 0);
      }
    }
  }
#pragma unroll
  for (int cs = 0; cs < 2; cs++)
#pragma unroll
    for (int s = 0; s < 2; s++) {
      int site = nB + s * 16 + ln;
      float4 g = make_float4(acc[cs][s][0], acc[cs][s][1], acc[cs][s][2], acc[cs][s][3]);
      *(float4*)&G[(pq * 2048 + site) * 128 + coW + cs * 16 + quad * 4] = g;
    }
}

// ---------- out: combine G per class, bias+relu, 1x1 conv to 3ch, splat ------
__global__ __launch_bounds__(256) void k_out(const float* __restrict__ G,
                                             const float* __restrict__ bc1,
                                             const float* __restrict__ w3,
                                             const float* __restrict__ b3,
                                             float* __restrict__ xhat,
                                             const float* __restrict__ loss_acc,
                                             float* __restrict__ out_loss) {
  __shared__ float Tb[9][128];
  __shared__ float part[9][3][8];
  __shared__ float vals[9][3];
  int bj = blockIdx.x, bi = blockIdx.y, b = blockIdx.z;
  int s = bi * 8 + bj;
  int n = b * 64 + s;
  int tid = threadIdx.x;
  if (bj == 0 && bi == 0 && b == 0 && tid == 0)
    out_loss[0] = loss_acc[0] * 1.25f / 131072.0f;
  int co = tid & 127, h = tid >> 7;
  const int rset[3][2] = {{0, 1}, {2, 2}, {3, 4}};
  const int rcnt[3] = {2, 1, 2};
  for (int cls = h; cls < 9; cls += 2) {
    int r = cls / 3, c = cls - r * 3;
    float sum = bc1[co];
    for (int iy = 0; iy < rcnt[r]; iy++) {
      int py = rset[r][iy];
      for (int ix = 0; ix < rcnt[c]; ix++) {
        int px = rset[c][ix];
        sum += G[((py * 5 + px) * 2048 + n) * 128 + co];
      }
    }
    Tb[cls][co] = fmaxf(sum, 0.f);
  }
  __syncthreads();
  if (tid < 216) {
    int cls = tid / 24, rem = tid - cls * 24;
    int cc = rem >> 3, seg = rem & 7;
    float ss = 0.f;
#pragma unroll
    for (int d = 0; d < 16; d++) ss = fmaf(w3[cc * 128 + seg * 16 + d], Tb[cls][seg * 16 + d], ss);
    part[cls][cc][seg] = ss;
  }
  __syncthreads();
  if (tid < 27) {
    int cls = tid / 3, cc = tid - cls * 3;
    float ss = b3[cc];
#pragma unroll
    for (int seg = 0; seg < 8; seg++) ss += part[cls][cc][seg];
    vals[cls][cc] = ss;
  }
  __syncthreads();
  for (int i = tid; i < 768; i += 256) {
    int cc = i >> 8, p = i & 255;
    int ry = p >> 4, rx = p & 15;
    int rcls = (ry == 0) ? 0 : ((ry == 15) ? 2 : 1);
    int ccls = (rx == 0) ? 0 : ((rx == 15) ? 2 : 1);
    xhat[((b * 3 + cc) * 128 + bi * 16 + ry) * 128 + bj * 16 + rx] =
        vals[rcls * 3 + ccls][cc];
  }
}

extern "C" void kernel_launch(void* const* d_in, const int* in_sizes, int n_in,
                              void* d_out, int out_size, void* d_ws, size_t ws_size,
                              hipStream_t stream) {
  const float* x   = (const float*)d_in[0];
  const float* w1  = (const float*)d_in[1];
  const float* b1  = (const float*)d_in[2];
  const float* w2  = (const float*)d_in[3];
  const float* b2  = (const float*)d_in[4];
  const float* wp  = (const float*)d_in[5];
  const float* pb  = (const float*)d_in[6];
  const float* cb  = (const float*)d_in[7];
  const float* wd  = (const float*)d_in[8];
  const float* db  = (const float*)d_in[9];
  const float* wc1 = (const float*)d_in[10];
  const float* bc1 = (const float*)d_in[11];
  const float* wc2 = (const float*)d_in[12];
  const float* bc2 = (const float*)d_in[13];
  float* out = (float*)d_out;
  float* ws  = (float*)d_ws;

  // workspace (float offsets):
  _Float16* h1h = (_Float16*)(ws);             // [0, 8388640) f16 plane (+tail)
  float* h2     = ws + 16777280;               // 4194304
  _Float16* Wh  = (_Float16*)(ws + 20971584);  // 73728 fl
  _Float16* Wl  = (_Float16*)(ws + 21045312);  // 73728 fl
  float* w1t    = ws + 21119040;               // 3456
  float* wpT    = ws + 21122496;               // 8192
  float* wdT    = ws + 21130688;               // 8192
  float* cbT    = ws + 21138880;               // 32768
  _Float16* Ahd = (_Float16*)(ws + 21171648);  // 204800 fl
  _Float16* Ald = (_Float16*)(ws + 21376448);  // 204800 fl -> end 21581248
  // overlays inside dead h1h region (valid after conv2):
  float* G       = ws;                         // [0, 6553600)
  _Float16* Yh   = (_Float16*)(ws + 6553600);  // 131136 fl (2049*128 f16)
  _Float16* Yl   = (_Float16*)(ws + 6684736);  // 131136 fl
  float* lossacc = ws + 6815872;               // 1

  float* o_xhat = out;
  float* o_idx  = out + 1572864;
  float* o_loss = out + 1574912;
  float* o_ze   = out + 1574913;

  static bool s_attr_done = false;
  if (!s_attr_done) {
    (void)hipFuncSetAttribute((const void*)k_conv2,
                              hipFuncAttributeMaxDynamicSharedMemorySize, C2_LDS);
    s_attr_done = true;
  }

  k_prep<<<dim3(153), 256, 0, stream>>>(w2, w1, wp, wd, wc1, cb,
                                        w1t, wpT, wdT, cbT, Ahd, Ald, Wh, Wl, h1h);
  k_conv1<<<dim3(4, 16, 32), 256, 0, stream>>>(x, w1t, b1, h1h);
  k_conv2<<<dim3(256), 512, C2_LDS, stream>>>(h1h, Wh, Wl, b2, h2);
  k_poolproj<<<dim3(128), 256, 0, stream>>>(h2, wpT, pb, o_ze, lossacc);
  k_vqdproj<<<dim3(2048), 64, 0, stream>>>(o_ze, cbT, cb, wdT, db, o_idx, Yh, Yl, lossacc);
  k_dec<<<dim3(1600), 256, 0, stream>>>(Yh, Yl, Ahd, Ald, G);
  k_out<<<dim3(8, 8, 32), 256, 0, stream>>>(G, bc1, wc2, bc2, o_xhat, lossacc, o_loss);
}

// Round 6
// 249.793 us; speedup vs baseline: 1.3178x; 1.0529x over previous
//
#include <hip/hip_runtime.h>
#include <math.h>

// ---------------------------------------------------------------------------
// VQVAE forward. v15: k_vqdproj parallelism fix. v14 profile: vqdproj is now
// the top kernel (48.8 us) with VALUBusy 17% / occupancy 17% -- 64-thread
// (1-wave) blocks, each lane serially walking 8 codes x 64 dims of f64 +
// 512 L2 loads = latency-exposed. v15: 256-thread blocks (4 waves), wave w
// owns codes [w*128, w*128+128), 2 codes/lane; per-code f64 math is
// BIT-IDENTICAL to v14 (same accumulator order) and the reduction preserves
// smallest-index-on-tie, so idx/loss outputs are unchanged. dproj epilogue:
// 128 threads x 1 output. Everything else unchanged from v14.
// ---------------------------------------------------------------------------

typedef _Float16 f16x8 __attribute__((ext_vector_type(8)));
typedef float f32x4 __attribute__((ext_vector_type(4)));

#define H1N 16777216        // elements in h1 plane; zero tail after
#define YTAIL (2048 * 128)  // zero page in Yh/Yl for OOB shifts

// ---------- prep: A-agg (0..127), W-split (128..143), cbT (144..151), misc --
__global__ __launch_bounds__(256) void k_prep(const float* __restrict__ w2,
                                              const float* __restrict__ w1,
                                              const float* __restrict__ wp,
                                              const float* __restrict__ wd,
                                              const float* __restrict__ wd1,
                                              const float* __restrict__ cb,
                                              float* __restrict__ w1t,
                                              float* __restrict__ wpT,
                                              float* __restrict__ wdT,
                                              float* __restrict__ cbT,
                                              _Float16* __restrict__ Ah,
                                              _Float16* __restrict__ Al,
                                              _Float16* __restrict__ Wh,
                                              _Float16* __restrict__ Wl,
                                              _Float16* __restrict__ h1h) {
  int bx = blockIdx.x, tid = threadIdx.x;
  if (bx < 128) {  // ---- A aggregation, block = co, lanes = ci (writes coalesced)
    __shared__ float wrow[1152];
    int co = bx;
    for (int i = tid; i < 1152; i += 256) wrow[i] = wd1[co * 1152 + i];
    __syncthreads();
    if (tid < 128) {
      int ci = tid;
      float w[9];
#pragma unroll
      for (int t = 0; t < 9; t++) w[t] = wrow[ci * 9 + t];
      float rx[3][5];
#pragma unroll
      for (int ky = 0; ky < 3; ky++) {
        float a0 = w[ky * 3 + 0], a1 = w[ky * 3 + 1], a2 = w[ky * 3 + 2];
        rx[ky][0] = a0; rx[ky][1] = a1 + a2; rx[ky][2] = a0 + a1 + a2;
        rx[ky][3] = a0 + a1; rx[ky][4] = a2;
      }
#pragma unroll
      for (int px = 0; px < 5; px++) {
        float s0 = rx[0][px], s1 = rx[1][px], s2 = rx[2][px];
        float ry[5];
        ry[0] = s0; ry[1] = s1 + s2; ry[2] = s0 + s1 + s2; ry[3] = s0 + s1; ry[4] = s2;
#pragma unroll
        for (int py = 0; py < 5; py++) {
          int pq = py * 5 + px;
          float v = ry[py];
          _Float16 h = (_Float16)v;
          int o = (pq * 128 + co) * 128 + ci;
          Ah[o] = h;
          Al[o] = (_Float16)(v - (float)h);
        }
      }
    }
    return;
  }
  if (bx < 144) {  // ---- W f16-split: 8 co per block, LDS-staged, coalesced RW
    __shared__ float wst[9216];
    int co0 = (bx - 128) * 8;
    for (int i = tid; i < 9216; i += 256) wst[i] = w2[co0 * 1152 + i];
    __syncthreads();
    for (int i = tid; i < 9216; i += 256) {
      int co = i / 1152, r = i - co * 1152;
      int tap = r >> 7, ci = r & 127;
      float v = wst[co * 1152 + ci * 9 + tap];
      _Float16 h = (_Float16)v;
      int o = (tap * 128 + co0 + co) * 128 + ci;
      Wh[o] = h;
      Wl[o] = (_Float16)(v - (float)h);
    }
    return;
  }
  if (bx < 152) {  // ---- cbT tile transpose (64 k x 64 d), padded LDS
    __shared__ float cbs[64 * 65];
    int k0 = (bx - 144) * 64;
    for (int i = tid; i < 4096; i += 256) {
      int k = i >> 6, d = i & 63;
      cbs[k * 65 + d] = cb[(k0 + k) * 64 + d];
    }
    __syncthreads();
    for (int i = tid; i < 4096; i += 256) {
      int d = i >> 6, k = i & 63;
      cbT[d * 512 + k0 + k] = cbs[k * 65 + d];
    }
    return;
  }
  // ---- misc small transposes + h1 zero tail (writes lane-contiguous)
  for (int i = tid; i < 3456; i += 256) {  // w1t[t][co] = w1[co][t]
    int co = i & 127, t = i >> 7;
    w1t[t * 128 + co] = w1[co * 27 + t];
  }
  for (int i = tid; i < 8192; i += 256) {  // wpT[k][d] = wp[d][k]
    int d = i & 63, k = i >> 6;
    wpT[k * 64 + d] = wp[d * 128 + k];
  }
  for (int i = tid; i < 8192; i += 256) {  // wdT[d][co] = wd[co][d]
    int co = i & 127, d = i >> 7;
    wdT[d * 128 + co] = wd[co * 64 + d];
  }
  if (tid < 64) h1h[H1N + tid] = (_Float16)0.f;
}

// ---------- conv1: (32,3,128,128) -> h1 f16 [g][b][oh][ow][8ci] -------------
__global__ __launch_bounds__(256) void k_conv1(const float* __restrict__ x,
                                               const float* __restrict__ w1t,
                                               const float* __restrict__ b1,
                                               _Float16* __restrict__ h1h) {
  __shared__ float E[3][9][68];
  __shared__ float O[3][9][68];
  int co_t = blockIdx.x, oh_t = blockIdx.y, b = blockIdx.z;
  int oh0 = oh_t * 4;
  int tid = threadIdx.x;
  int wv = __builtin_amdgcn_readfirstlane(tid >> 6);
  int l = tid & 63;
  int coB = co_t * 32 + wv * 8;

  for (int idx = tid; idx < 1728; idx += 256) {
    int p = idx & 63, r = idx >> 6;
    int ci = r / 9, lr = r - ci * 9;
    int ih = 2 * oh0 - 1 + lr;
    float2 v = make_float2(0.f, 0.f);
    if ((unsigned)ih < 128u)
      v = *(const float2*)&x[((b * 3 + ci) * 128 + ih) * 128 + 2 * p];
    E[ci][lr][p] = v.x;
    O[ci][lr][p + 1] = v.y;
  }
  if (tid < 27) {
    int ci = tid / 9, lr = tid - ci * 9;
    O[ci][lr][0] = 0.f;
  }
  __syncthreads();

  int ohl = l >> 4, ow0 = (l & 15) * 4;
  int oh = oh0 + ohl;
  float4 acc[8];
#pragma unroll
  for (int q = 0; q < 8; q++) {
    float bv = b1[coB + q];
    acc[q] = make_float4(bv, bv, bv, bv);
  }
#pragma unroll
  for (int ci = 0; ci < 3; ci++) {
#pragma unroll
    for (int ky = 0; ky < 3; ky++) {
      int lr = 2 * ohl + ky;
      float4 ev = *(float4*)&E[ci][lr][ow0];
      float4 od = *(float4*)&O[ci][lr][ow0];
      float o4 = O[ci][lr][ow0 + 4];
      const float* wr = w1t + (ci * 9 + ky * 3) * 128 + coB;
#pragma unroll
      for (int q = 0; q < 8; q++) {
        float wa = wr[q], wb = wr[128 + q], wc = wr[256 + q];
        acc[q].x = fmaf(wa, od.x, acc[q].x);
        acc[q].x = fmaf(wb, ev.x, acc[q].x);
        acc[q].x = fmaf(wc, od.y, acc[q].x);
        acc[q].y = fmaf(wa, od.y, acc[q].y);
        acc[q].y = fmaf(wb, ev.y, acc[q].y);
        acc[q].y = fmaf(wc, od.z, acc[q].y);
        acc[q].z = fmaf(wa, od.z, acc[q].z);
        acc[q].z = fmaf(wb, ev.z, acc[q].z);
        acc[q].z = fmaf(wc, od.w, acc[q].z);
        acc[q].w = fmaf(wa, od.w, acc[q].w);
        acc[q].w = fmaf(wb, ev.w, acc[q].w);
        acc[q].w = fmaf(wc, o4,   acc[q].w);
      }
    }
  }
  int g = coB >> 3;
  int pbase = ((g * 32 + b) * 64 + oh) * 64;
#pragma unroll
  for (int oi = 0; oi < 4; oi++) {
    f16x8 hv;
#pragma unroll
    for (int q = 0; q < 8; q++)
      hv[q] = (_Float16)fmaxf(((const float*)&acc[q])[oi], 0.f);
    *(f16x8*)&h1h[(pbase + ow0 + oi) * 8] = hv;
  }
}

// ---------- conv2: 2-term split MFMA (Al*Bh + Ah*Bh), v10 structure ---------
// grid 256 = (b(32) x ohq(8)); block 512 = 8 waves. wave w: co-group (w&3),
// row-group rw=(w>>2) -> rows oh0+2*rw..+1. LDS B (37.44 KB/buffer, dbuf):
// chunk c = (g*9 + r)*65 + (ph? 33+u : u), g=ci8-group(4), r=row(9:
// ih=2*oh0-1+r), ph=0: iw=2u-1, ph=1: iw=2u. Stage: 4 full 512-thread
// global_load_lds rounds + 292 masked tail; issue stage(nxt) -> compute(cur)
// -> one __syncthreads per step.
#define C2_CHUNKS 2340
#define C2_BUF (C2_CHUNKS * 8)   // f16 elems per buffer
#define C2_LDS (2 * C2_BUF * 2)  // bytes = 74880
#define C2_STEP 4194304          // h1 element advance per +32ci step

__global__ __launch_bounds__(512, 2) void k_conv2(const _Float16* __restrict__ h1h,
                                                  const _Float16* __restrict__ Wh,
                                                  const _Float16* __restrict__ Wl,
                                                  const float* __restrict__ b2,
                                                  float* __restrict__ h2) {
  extern __shared__ _Float16 Bbuf[];
  int bx = blockIdx.x;
  int b = bx >> 3, ohq = bx & 7;
  int oh0 = ohq * 4;
  int tid = threadIdx.x;
  int w = tid >> 6, l = tid & 63;
  int cw = w & 3, rw = w >> 2;
  int ln = l & 15, quad = l >> 4;
  int coW = cw * 32;
  int kq = quad * 8;

  // ---- staging descriptors: 5 chunks/thread (last partial, tid<292) ----
  int cursrc[5];
  int adv[5];
#pragma unroll
  for (int k = 0; k < 5; k++) {
    int c = (k < 4) ? (tid + k * 512) : (2048 + tid);
    if (c < C2_CHUNKS) {
      int q = c / 65, rem = c - q * 65;
      int ph = rem >= 33;
      int u = ph ? rem - 33 : rem;
      int r = q % 9, g = q / 9;
      int iw = ph ? 2 * u : 2 * u - 1;
      int ih = 2 * oh0 - 1 + r;
      bool ok = (ih >= 0) && (iw >= 0) && (iw < 64);
      cursrc[k] = ok ? ((g * 32 + b) * 64 + ih) * 512 + iw * 8 : H1N;
      adv[k] = ok ? C2_STEP : 0;
    } else {
      cursrc[k] = H1N;
      adv[k] = 0;
    }
  }

#define C2_STAGE(DST)                                                          \
  {                                                                            \
    _Pragma("unroll") for (int k = 0; k < 4; k++) {                            \
      __builtin_amdgcn_global_load_lds(                                        \
          (const __attribute__((address_space(1))) void*)(h1h + cursrc[k]),    \
          (__attribute__((address_space(3))) void*)&Bbuf[(DST) +               \
                                                         (tid + k * 512) * 8], \
          16, 0, 0);                                                           \
      cursrc[k] += adv[k];                                                     \
    }                                                                          \
    if (tid < 292) {                                                           \
      __builtin_amdgcn_global_load_lds(                                        \
          (const __attribute__((address_space(1))) void*)(h1h + cursrc[4]),    \
          (__attribute__((address_space(3))) void*)&Bbuf[(DST) +               \
                                                         (2048 + tid) * 8],    \
          16, 0, 0);                                                           \
    }                                                                          \
    cursrc[4] += adv[4];                                                       \
  }

  int curoff = 0;
  C2_STAGE(0);      // prologue: stage K-step 0 into buffer 0
  __syncthreads();  // drain + barrier

  f32x4 acc[2][4] = {};  // [cs][s]  s = (row-in-pair<<1)|col-half
  for (int step = 0; step < 4; step++) {
    int nxt = curoff ^ C2_BUF;
    if (step < 3) C2_STAGE(nxt);  // issue next K-step's loads
    const int ci0 = step * 32;
#pragma unroll
    for (int ky = 0; ky < 3; ky++) {
#pragma unroll
      for (int kx = 0; kx < 3; kx++) {
        int tap = ky * 3 + kx;
        const int wbase = (tap * 128 + coW + ln) * 128 + ci0 + kq;
        f16x8 Ah0 = *(const f16x8*)&Wh[wbase];
        f16x8 Al0 = *(const f16x8*)&Wl[wbase];
        f16x8 Ah1 = *(const f16x8*)&Wh[wbase + 2048];  // +16 co
        f16x8 Al1 = *(const f16x8*)&Wl[wbase + 2048];
#pragma unroll
        for (int s = 0; s < 4; s++) {
          int owl = (s & 1) * 16 + ln;
          int r = 4 * rw + 2 * (s >> 1) + ky;
          int base = (quad * 9 + r) * 65;
          int uoff = (kx == 1) ? (33 + owl) : (owl + (kx == 2));
          f16x8 Bh = *(const f16x8*)&Bbuf[curoff + (base + uoff) * 8];
          acc[0][s] = __builtin_amdgcn_mfma_f32_16x16x32_f16(Al0, Bh, acc[0][s], 0, 0, 0);
          acc[0][s] = __builtin_amdgcn_mfma_f32_16x16x32_f16(Ah0, Bh, acc[0][s], 0, 0, 0);
          acc[1][s] = __builtin_amdgcn_mfma_f32_16x16x32_f16(Al1, Bh, acc[1][s], 0, 0, 0);
          acc[1][s] = __builtin_amdgcn_mfma_f32_16x16x32_f16(Ah1, Bh, acc[1][s], 0, 0, 0);
        }
      }
    }
    __syncthreads();  // loads into nxt done; all done reading cur
    curoff = nxt;
  }
  // epilogue: C row = co (quad*4+reg), col = px (lane&15)
#pragma unroll
  for (int cs = 0; cs < 2; cs++)
#pragma unroll
    for (int s = 0; s < 4; s++) {
      int oh = oh0 + 2 * rw + (s >> 1);
      int ow = (s & 1) * 16 + ln;
#pragma unroll
      for (int r = 0; r < 4; r++) {
        int co = coW + cs * 16 + quad * 4 + r;
        h2[((b * 128 + co) * 32 + oh) * 32 + ow] = fmaxf(acc[cs][s][r] + b2[co], 0.f);
      }
    }
#undef C2_STAGE
}

// ---------- pool(4x4 mean) + proj(1x1,128->64); grid 128 (b x quarter) ------
__global__ __launch_bounds__(256) void k_poolproj(const float* __restrict__ h2,
                                                  const float* __restrict__ wpT,
                                                  const float* __restrict__ pb,
                                                  float* __restrict__ z_e_out,
                                                  float* __restrict__ lossacc) {
  __shared__ float hp[128][16];
  __shared__ float Ws[128][64];
  int bx = blockIdx.x, tid = threadIdx.x;
  int b = bx >> 2, quarter = bx & 3;
  if (bx == 0 && tid == 0) lossacc[0] = 0.f;
  for (int i = tid; i < 8192; i += 256) Ws[i >> 6][i & 63] = wpT[i];
  for (int i = tid; i < 2048; i += 256) {
    int ci = i >> 4, pl = i & 15;
    int pi = quarter * 16 + pl;
    int bi = pi >> 3, bj = pi & 7;
    const float* src = &h2[((b * 128 + ci) * 32 + bi * 4) * 32 + bj * 4];
    float4 r0 = *(const float4*)src;
    float4 r1 = *(const float4*)(src + 32);
    float4 r2 = *(const float4*)(src + 64);
    float4 r3 = *(const float4*)(src + 96);
    float s = r0.x + r0.y + r0.z + r0.w + r1.x + r1.y + r1.z + r1.w +
              r2.x + r2.y + r2.z + r2.w + r3.x + r3.y + r3.z + r3.w;
    hp[ci][pl] = s * 0.0625f;
  }
  __syncthreads();
  int d = tid >> 2, s0 = (tid & 3) * 4;
  float4 acc = make_float4(0.f, 0.f, 0.f, 0.f);
  for (int k = 0; k < 128; k++) {
    float a = Ws[k][d];
    float4 h = *(float4*)&hp[k][s0];
    acc.x = fmaf(a, h.x, acc.x);
    acc.y = fmaf(a, h.y, acc.y);
    acc.z = fmaf(a, h.z, acc.z);
    acc.w = fmaf(a, h.w, acc.w);
  }
  float bv = pb[d];
  float4 r4 = make_float4(acc.x + bv, acc.y + bv, acc.z + bv, acc.w + bv);
  *(float4*)&z_e_out[(b * 64 + d) * 64 + quarter * 16 + s0] = r4;
}

// ---------- VQ argmin + loss + dproj; grid 2048 x 256 (4 waves) -------------
// wave w owns codes [w*128, w*128+128), 2/lane; per-code f64 distance math is
// bit-identical to the 1-wave version (same accumulator order); reduction
// preserves smallest-index-on-tie (wave shuffle -> ascending 4-way LDS fold).
__global__ __launch_bounds__(256) void k_vqdproj(const float* __restrict__ z_e,
                                                 const float* __restrict__ cbT,
                                                 const float* __restrict__ cb,
                                                 const float* __restrict__ wdT,
                                                 const float* __restrict__ db,
                                                 float* __restrict__ idx_f,
                                                 _Float16* __restrict__ Yh,
                                                 _Float16* __restrict__ Yl,
                                                 float* __restrict__ loss_acc) {
  __shared__ float zs[64];
  __shared__ float zqv[64];
  __shared__ double wbst[4];
  __shared__ int wbi[4];
  int n = blockIdx.x, tid = threadIdx.x;
  int b = n >> 6, pi = n & 63;
  if (tid < 64) zs[tid] = z_e[(b * 64 + tid) * 64 + pi];
  if (n == 0 && tid < 64) {  // zero tail page for shifted reads in k_dec
    Yh[YTAIL + tid] = (_Float16)0.f;
    Yh[YTAIL + 64 + tid] = (_Float16)0.f;
    Yl[YTAIL + tid] = (_Float16)0.f;
    Yl[YTAIL + 64 + tid] = (_Float16)0.f;
  }
  __syncthreads();
  int w = tid >> 6, lane = tid & 63;
  double best = 1e300;
  int bi = 0;
#pragma unroll
  for (int j = 0; j < 2; j++) {
    int k = w * 128 + j * 64 + lane;
    double a0 = 0.0, a1 = 0.0, a2 = 0.0, a3 = 0.0;
#pragma unroll 4
    for (int d = 0; d < 64; d += 4) {
      double f0 = (double)zs[d] - (double)cbT[d * 512 + k];
      double f1 = (double)zs[d + 1] - (double)cbT[(d + 1) * 512 + k];
      double f2 = (double)zs[d + 2] - (double)cbT[(d + 2) * 512 + k];
      double f3 = (double)zs[d + 3] - (double)cbT[(d + 3) * 512 + k];
      a0 = fma(f0, f0, a0);
      a1 = fma(f1, f1, a1);
      a2 = fma(f2, f2, a2);
      a3 = fma(f3, f3, a3);
    }
    double acc = (a0 + a1) + (a2 + a3);
    if (acc < best) { best = acc; bi = k; }
  }
  for (int m = 1; m < 64; m <<= 1) {
    double ob = __shfl_xor(best, m, 64);
    int oi = __shfl_xor(bi, m, 64);
    if (ob < best || (ob == best && oi < bi)) { best = ob; bi = oi; }
  }
  if (lane == 0) { wbst[w] = best; wbi[w] = bi; }
  __syncthreads();
  best = wbst[0];
  bi = wbi[0];
#pragma unroll
  for (int q = 1; q < 4; q++) {
    double ob = wbst[q];
    int oi = wbi[q];
    if (ob < best || (ob == best && oi < bi)) { best = ob; bi = oi; }
  }
  if (tid < 64) {  // wave 0: loss + zq staging
    float zq_l = cb[bi * 64 + tid];
    float e = zq_l - zs[tid];
    float sq = e * e;
    for (int m = 1; m < 64; m <<= 1) sq += __shfl_xor(sq, m, 64);
    if (tid == 0) {
      idx_f[n] = (float)bi;
      atomicAdd(loss_acc, sq);
    }
    zqv[tid] = zq_l;
  }
  __syncthreads();
  if (tid < 128) {  // dproj: one co per thread
    float a = db[tid];
#pragma unroll 4
    for (int d = 0; d < 64; d++) a = fmaf(wdT[d * 128 + tid], zqv[d], a);
    float y = fmaxf(a, 0.f);
    _Float16 h = (_Float16)y;
    Yh[n * 128 + tid] = h;
    Yl[n * 128 + tid] = (_Float16)(y - (float)h);
  }
}

// ---------- dec: f16-split MFMA, G[pq][n][co] = A_pq * Yshift ----------
__global__ __launch_bounds__(256) void k_dec(const _Float16* __restrict__ Yh,
                                             const _Float16* __restrict__ Yl,
                                             const _Float16* __restrict__ Ah,
                                             const _Float16* __restrict__ Al,
                                             float* __restrict__ G) {
  int bxx = blockIdx.x;
  int pq = bxx >> 6, n_t = bxx & 63;
  int w = threadIdx.x >> 6, l = threadIdx.x & 63;
  int ln = l & 15, quad = l >> 4;
  int coW = w * 32;
  int nB = n_t * 32;
  int py = pq / 5, px = pq - py * 5;
  int dy = (py == 0) ? -1 : ((py == 4) ? 1 : 0);
  int dx = (px == 0) ? -1 : ((px == 4) ? 1 : 0);
  int src[2];
#pragma unroll
  for (int s = 0; s < 2; s++) {
    int n = nB + s * 16 + ln;
    int bb = n >> 6, s6 = n & 63;
    int sy = (s6 >> 3) + dy, sx = (s6 & 7) + dx;
    bool ok = ((unsigned)sy < 8u) && ((unsigned)sx < 8u);
    src[s] = ok ? ((bb * 64 + sy * 8 + sx) * 128) : YTAIL;
  }
  int kq = quad * 8;
  f32x4 acc[2][2] = {};
#pragma unroll 2
  for (int ci0 = 0; ci0 < 128; ci0 += 32) {
    const int wbase = (pq * 128 + coW + ln) * 128 + ci0 + kq;
    f16x8 Ah0 = *(const f16x8*)&Ah[wbase];
    f16x8 Al0 = *(const f16x8*)&Al[wbase];
    f16x8 Ah1 = *(const f16x8*)&Ah[wbase + 2048];
    f16x8 Al1 = *(const f16x8*)&Al[wbase + 2048];
    f16x8 Bh[2], Bl[2];
#pragma unroll
    for (int s = 0; s < 2; s++) {
      Bh[s] = *(const f16x8*)&Yh[src[s] + ci0 + kq];
      Bl[s] = *(const f16x8*)&Yl[src[s] + ci0 + kq];
    }
#pragma unroll
    for (int cs = 0; cs < 2; cs++) {
      f16x8 ah = cs ? Ah1 : Ah0;
      f16x8 al = cs ? Al1 : Al0;
#pragma unroll
      for (int s = 0; s < 2; s++) {
        acc[cs][s] = __builtin_amdgcn_mfma_f32_16x16x32_f16(al, Bh[s], acc[cs][s], 0, 0, 0);
        acc[cs][s] = __builtin_amdgcn_mfma_f32_16x16x32_f16(ah, Bl[s], acc[cs][s], 0, 0, 0);
        acc[cs][s] = __builtin_amdgcn_mfma_f32_16x16x32_f16(ah, Bh[s], acc[cs][s], 0, 0, 0);
      }
    }
  }
#pragma unroll
  for (int cs = 0; cs < 2; cs++)
#pragma unroll
    for (int s = 0; s < 2; s++) {
      int site = nB + s * 16 + ln;
      float4 g = make_float4(acc[cs][s][0], acc[cs][s][1], acc[cs][s][2], acc[cs][s][3]);
      *(float4*)&G[(pq * 2048 + site) * 128 + coW + cs * 16 + quad * 4] = g;
    }
}

// ---------- out: combine G per class, bias+relu, 1x1 conv to 3ch, splat ------
__global__ __launch_bounds__(256) void k_out(const float* __restrict__ G,
                                             const float* __restrict__ bc1,
                                             const float* __restrict__ w3,
                                             const float* __restrict__ b3,
                                             float* __restrict__ xhat,
                                             const float* __restrict__ loss_acc,
                                             float* __restrict__ out_loss) {
  __shared__ float Tb[9][128];
  __shared__ float part[9][3][8];
  __shared__ float vals[9][3];
  int bj = blockIdx.x, bi = blockIdx.y, b = blockIdx.z;
  int s = bi * 8 + bj;
  int n = b * 64 + s;
  int tid = threadIdx.x;
  if (bj == 0 && bi == 0 && b == 0 && tid == 0)
    out_loss[0] = loss_acc[0] * 1.25f / 131072.0f;
  int co = tid & 127, h = tid >> 7;
  const int rset[3][2] = {{0, 1}, {2, 2}, {3, 4}};
  const int rcnt[3] = {2, 1, 2};
  for (int cls = h; cls < 9; cls += 2) {
    int r = cls / 3, c = cls - r * 3;
    float sum = bc1[co];
    for (int iy = 0; iy < rcnt[r]; iy++) {
      int py = rset[r][iy];
      for (int ix = 0; ix < rcnt[c]; ix++) {
        int px = rset[c][ix];
        sum += G[((py * 5 + px) * 2048 + n) * 128 + co];
      }
    }
    Tb[cls][co] = fmaxf(sum, 0.f);
  }
  __syncthreads();
  if (tid < 216) {
    int cls = tid / 24, rem = tid - cls * 24;
    int cc = rem >> 3, seg = rem & 7;
    float ss = 0.f;
#pragma unroll
    for (int d = 0; d < 16; d++) ss = fmaf(w3[cc * 128 + seg * 16 + d], Tb[cls][seg * 16 + d], ss);
    part[cls][cc][seg] = ss;
  }
  __syncthreads();
  if (tid < 27) {
    int cls = tid / 3, cc = tid - cls * 3;
    float ss = b3[cc];
#pragma unroll
    for (int seg = 0; seg < 8; seg++) ss += part[cls][cc][seg];
    vals[cls][cc] = ss;
  }
  __syncthreads();
  for (int i = tid; i < 768; i += 256) {
    int cc = i >> 8, p = i & 255;
    int ry = p >> 4, rx = p & 15;
    int rcls = (ry == 0) ? 0 : ((ry == 15) ? 2 : 1);
    int ccls = (rx == 0) ? 0 : ((rx == 15) ? 2 : 1);
    xhat[((b * 3 + cc) * 128 + bi * 16 + ry) * 128 + bj * 16 + rx] =
        vals[rcls * 3 + ccls][cc];
  }
}

extern "C" void kernel_launch(void* const* d_in, const int* in_sizes, int n_in,
                              void* d_out, int out_size, void* d_ws, size_t ws_size,
                              hipStream_t stream) {
  const float* x   = (const float*)d_in[0];
  const float* w1  = (const float*)d_in[1];
  const float* b1  = (const float*)d_in[2];
  const float* w2  = (const float*)d_in[3];
  const float* b2  = (const float*)d_in[4];
  const float* wp  = (const float*)d_in[5];
  const float* pb  = (const float*)d_in[6];
  const float* cb  = (const float*)d_in[7];
  const float* wd  = (const float*)d_in[8];
  const float* db  = (const float*)d_in[9];
  const float* wc1 = (const float*)d_in[10];
  const float* bc1 = (const float*)d_in[11];
  const float* wc2 = (const float*)d_in[12];
  const float* bc2 = (const float*)d_in[13];
  float* out = (float*)d_out;
  float* ws  = (float*)d_ws;

  // workspace (float offsets):
  _Float16* h1h = (_Float16*)(ws);             // [0, 8388640) f16 plane (+tail)
  float* h2     = ws + 16777280;               // 4194304
  _Float16* Wh  = (_Float16*)(ws + 20971584);  // 73728 fl
  _Float16* Wl  = (_Float16*)(ws + 21045312);  // 73728 fl
  float* w1t    = ws + 21119040;               // 3456
  float* wpT    = ws + 21122496;               // 8192
  float* wdT    = ws + 21130688;               // 8192
  float* cbT    = ws + 21138880;               // 32768
  _Float16* Ahd = (_Float16*)(ws + 21171648);  // 204800 fl
  _Float16* Ald = (_Float16*)(ws + 21376448);  // 204800 fl -> end 21581248
  // overlays inside dead h1h region (valid after conv2):
  float* G       = ws;                         // [0, 6553600)
  _Float16* Yh   = (_Float16*)(ws + 6553600);  // 131136 fl (2049*128 f16)
  _Float16* Yl   = (_Float16*)(ws + 6684736);  // 131136 fl
  float* lossacc = ws + 6815872;               // 1

  float* o_xhat = out;
  float* o_idx  = out + 1572864;
  float* o_loss = out + 1574912;
  float* o_ze   = out + 1574913;

  static bool s_attr_done = false;
  if (!s_attr_done) {
    (void)hipFuncSetAttribute((const void*)k_conv2,
                              hipFuncAttributeMaxDynamicSharedMemorySize, C2_LDS);
    s_attr_done = true;
  }

  k_prep<<<dim3(153), 256, 0, stream>>>(w2, w1, wp, wd, wc1, cb,
                                        w1t, wpT, wdT, cbT, Ahd, Ald, Wh, Wl, h1h);
  k_conv1<<<dim3(4, 16, 32), 256, 0, stream>>>(x, w1t, b1, h1h);
  k_conv2<<<dim3(256), 512, C2_LDS, stream>>>(h1h, Wh, Wl, b2, h2);
  k_poolproj<<<dim3(128), 256, 0, stream>>>(h2, wpT, pb, o_ze, lossacc);
  k_vqdproj<<<dim3(2048), 256, 0, stream>>>(o_ze, cbT, cb, wdT, db, o_idx, Yh, Yl, lossacc);
  k_dec<<<dim3(1600), 256, 0, stream>>>(Yh, Yl, Ahd, Ald, G);
  k_out<<<dim3(8, 8, 32), 256, 0, stream>>>(G, bc1, wc2, bc2, o_xhat, lossacc, o_loss);
}